// Round 5
// baseline (301.927 us; speedup 1.0000x reference)
//
#include <hip/hip_runtime.h>
#include <hip/hip_bf16.h>

#define BATCH   4
#define SEQ     2048
#define DMODEL  1024
#define NHEADS  16
#define DHEAD   64
#define MROWS   (BATCH*SEQ)        // 8192
#define QKV_N   (3*DMODEL)         // 3072
#define NEG_BIG (-1.0e30f)
#define WS_NEED ((size_t)MROWS * 2*DMODEL * sizeof(__hip_bfloat16))  // 33,554,432
#define SCALE_Q 0.18033688011112042f   // 0.125 * log2(e); folded into Q at projection

using bf16 = __hip_bfloat16;
typedef __attribute__((ext_vector_type(8))) short short8;
typedef __attribute__((ext_vector_type(4))) float floatx4;

// Static device buffers (module BSS; no hipMalloc)
__device__ __align__(16) unsigned short g_wqT[QKV_N * DMODEL];   // W_qkv^T bf16
__device__ __align__(16) unsigned short g_woT[DMODEL * DMODEL];  // W_out^T bf16
__device__ __align__(16) unsigned short g_xb [MROWS * DMODEL];   // x bf16

__device__ __forceinline__ unsigned short f2bf_rne(float f) {
    union { bf16 b; unsigned short u; } t;
    t.b = __float2bfloat16(f);
    return t.u;
}

// async global->LDS, 16B per lane; LDS dest = wave-uniform base + lane*16
__device__ __forceinline__ void gload_lds16(const void* g, void* l) {
    __builtin_amdgcn_global_load_lds(
        (const __attribute__((address_space(1))) unsigned*)g,
        (__attribute__((address_space(3))) unsigned*)l, 16, 0, 0);
}

// ---------------------------------------------------------------------------
// x fp32 -> bf16
// ---------------------------------------------------------------------------
__global__ __launch_bounds__(256) void cast_x(const float* __restrict__ x) {
    const size_t i = ((size_t)blockIdx.x*256 + threadIdx.x)*8;
    const float4 a = *(const float4*)(x + i);
    const float4 b = *(const float4*)(x + i + 4);
    union { uint4 u4; unsigned short us[8]; } o;
    o.us[0]=f2bf_rne(a.x); o.us[1]=f2bf_rne(a.y); o.us[2]=f2bf_rne(a.z); o.us[3]=f2bf_rne(a.w);
    o.us[4]=f2bf_rne(b.x); o.us[5]=f2bf_rne(b.y); o.us[6]=f2bf_rne(b.z); o.us[7]=f2bf_rne(b.w);
    *(uint4*)(g_xb + i) = o.u4;
}

// ---------------------------------------------------------------------------
// Weight transpose + cast: W fp32 [1024][N] -> dst bf16 [N][1024]
// ---------------------------------------------------------------------------
__global__ __launch_bounds__(256) void transcast_w(
    const float* __restrict__ W, int N, int which)
{
    unsigned short* dst = which ? g_woT : g_wqT;
    __shared__ unsigned short T[64][72];
    const int n0 = blockIdx.x * 64, k0 = blockIdx.y * 64;
    const int tid = threadIdx.x;
    const int r = tid >> 2, c0 = (tid & 3) * 16;

#pragma unroll
    for (int it = 0; it < 4; ++it) {
        const float4 v = *(const float4*)(W + (size_t)(k0 + r)*N + n0 + c0 + it*4);
        T[r][c0 + it*4 + 0] = f2bf_rne(v.x);
        T[r][c0 + it*4 + 1] = f2bf_rne(v.y);
        T[r][c0 + it*4 + 2] = f2bf_rne(v.z);
        T[r][c0 + it*4 + 3] = f2bf_rne(v.w);
    }
    __syncthreads();
    const int nr = tid >> 2, kc0 = (tid & 3) * 16;
#pragma unroll
    for (int it = 0; it < 2; ++it) {
        union { uint4 u4; unsigned short us[8]; } o;
#pragma unroll
        for (int j = 0; j < 8; j++) o.us[j] = T[kc0 + it*8 + j][nr];
        *(uint4*)(dst + (size_t)(n0 + nr)*DMODEL + k0 + kc0 + it*8) = o.u4;
    }
}

// ---------------------------------------------------------------------------
// 256x128 BK=64 phase-pipelined MFMA GEMM body (shared by qkv_proj/out_proj).
// 8 waves (512 thr), wave grid 4M x 2N, per-wave output 64x64.
// LDS 96 KiB: A 2buf x 32KB (32 subtiles), B 2buf x 16KB (16 subtiles).
// Subtile = 16 rows x 32 k x 2B = 1KB; 16B chunk c of row r at slot
// c ^ ((r>>1)&3) -> frag ds_read_b128 conflict-free.
// Phase schedule per K-tile t (stage tile t+1 into buf^1):
//  p0: read bf[4][2]+af(qm0); stage B'0,B'1,A'0,A'1; bar; 16 MFMA;
//      vmcnt(4) [drains A(t)2,A(t)3 - issued one tile ago]; bar
//  p1: read af(qm1);          stage A'2,A'3;          bar; 16 MFMA;
//      vmcnt(2) [drains B'0,B'1,A'0,A'1 - issued one phase ago]; bar
// No wait ever targets a load issued in the same phase.
// ---------------------------------------------------------------------------
template<int QKV_MODE>
__device__ __forceinline__ void gemm_body(
    const void* __restrict__ Av, const float* __restrict__ bias,
    void* __restrict__ C0, void* __restrict__ C1, void* __restrict__ C2)
{
    const unsigned short* A  = QKV_MODE ? g_xb  : (const unsigned short*)Av;
    const unsigned short* BT = QKV_MODE ? g_wqT : g_woT;
    constexpr int NBN = QKV_MODE ? 24 : 8;      // N/128
    constexpr int NWG = NBN * 32;               // * (M/256)

    __shared__ __align__(16) char smem[98304];  // A: 2x32KB @0; B: 2x16KB @65536
    char* const sA = smem;
    char* const sB = smem + 65536;

    // XCD-aware bijective swizzle: consecutive hw blocks on one XCD sweep bn
    const int orig = blockIdx.x;
    const int wgid = (orig & 7) * (NWG >> 3) + (orig >> 3);
    const int bm = wgid / NBN, bn = wgid % NBN;

    const int tid  = threadIdx.x;
    const int w    = tid >> 6, lane = tid & 63;
    const int m16  = lane & 15, quad = lane >> 4;
    const int rw   = w >> 1, cw = w & 1;

    // staging lane decomposition: slot chunk (r,c) holds data chunk c^((r>>1)&3)
    const int rL = lane >> 2;
    const int cD = (lane & 3) ^ ((lane >> 3) & 3);
    const unsigned short* gA = A  + (size_t)(bm*256 + rL)*DMODEL + cD*8;
    const unsigned short* gB = BT + (size_t)(bn*128 + rL)*DMODEL + cD*8;

    // frag-read lane offset (swizzled)
    const int laneRd = m16*64 + (quad ^ ((m16 >> 1) & 3))*16;

    floatx4 acc[2][2][4];   // [qm][i][j]
#pragma unroll
    for (int q = 0; q < 2; ++q)
#pragma unroll
        for (int i = 0; i < 2; ++i)
#pragma unroll
            for (int j = 0; j < 4; ++j) {
                acc[q][i][j][0]=0.f; acc[q][i][j][1]=0.f;
                acc[q][i][j][2]=0.f; acc[q][i][j][3]=0.f;
            }

    // A round a (0..3): wave w stages subtile (rg=4a+(w>>1), kh=w&1)
    auto stageA = [&](int buf, int a, int k0) {
        const int rg = 4*a + (w >> 1), kh = w & 1;
        gload_lds16(gA + (size_t)(rg*16)*DMODEL + k0 + kh*32,
                    sA + buf*32768 + (rg*2 + kh)*1024);
    };
    // B round b (0..1): wave w stages subtile (rg=4b+(w>>1), kh=w&1)
    auto stageB = [&](int buf, int b, int k0) {
        const int rg = 4*b + (w >> 1), kh = w & 1;
        gload_lds16(gB + (size_t)(rg*16)*DMODEL + k0 + kh*32,
                    sB + buf*16384 + (rg*2 + kh)*1024);
    };

    // ---- prologue: tile 0 -> buf 0
    stageB(0, 0, 0); stageB(0, 1, 0);
    stageA(0, 0, 0); stageA(0, 1, 0); stageA(0, 2, 0); stageA(0, 3, 0);
    asm volatile("s_waitcnt vmcnt(0)" ::: "memory");
    __builtin_amdgcn_s_barrier();

    const int NT = DMODEL / 64;   // 16
    for (int t = 0; t < NT; ++t) {
        const int  buf = t & 1;
        const int  k1  = (t + 1) * 64;
        const bool st  = (t + 1 < NT);
        char* const Ab = sA + buf*32768;
        char* const Bb = sB + buf*16384;

        // ================= phase 0: qm = 0 =================
        short8 bf[4][2], af[2][2];
#pragma unroll
        for (int j = 0; j < 4; ++j)
#pragma unroll
            for (int kh = 0; kh < 2; ++kh)
                bf[j][kh] = *(const short8*)(Bb + ((cw*4 + j)*2 + kh)*1024 + laneRd);
#pragma unroll
        for (int i = 0; i < 2; ++i)
#pragma unroll
            for (int kh = 0; kh < 2; ++kh)
                af[i][kh] = *(const short8*)(Ab + ((rw*2 + i)*2 + kh)*1024 + laneRd);

        if (st) { stageB(buf^1, 0, k1); stageB(buf^1, 1, k1);
                  stageA(buf^1, 0, k1); stageA(buf^1, 1, k1); }
        __builtin_amdgcn_s_barrier();

        __builtin_amdgcn_s_setprio(1);
#pragma unroll
        for (int i = 0; i < 2; ++i)
#pragma unroll
            for (int j = 0; j < 4; ++j) {
                acc[0][i][j] = __builtin_amdgcn_mfma_f32_16x16x32_bf16(
                    af[i][0], bf[j][0], acc[0][i][j], 0, 0, 0);
                acc[0][i][j] = __builtin_amdgcn_mfma_f32_16x16x32_bf16(
                    af[i][1], bf[j][1], acc[0][i][j], 0, 0, 0);
            }
        __builtin_amdgcn_s_setprio(0);

        if (st) { asm volatile("s_waitcnt vmcnt(4)" ::: "memory"); }
        else    { asm volatile("s_waitcnt vmcnt(0)" ::: "memory"); }
        __builtin_amdgcn_s_barrier();

        // ================= phase 1: qm = 1 =================
#pragma unroll
        for (int i = 0; i < 2; ++i)
#pragma unroll
            for (int kh = 0; kh < 2; ++kh)
                af[i][kh] = *(const short8*)(Ab + ((8 + rw*2 + i)*2 + kh)*1024 + laneRd);

        if (st) { stageA(buf^1, 2, k1); stageA(buf^1, 3, k1); }
        __builtin_amdgcn_s_barrier();

        __builtin_amdgcn_s_setprio(1);
#pragma unroll
        for (int i = 0; i < 2; ++i)
#pragma unroll
            for (int j = 0; j < 4; ++j) {
                acc[1][i][j] = __builtin_amdgcn_mfma_f32_16x16x32_bf16(
                    af[i][0], bf[j][0], acc[1][i][j], 0, 0, 0);
                acc[1][i][j] = __builtin_amdgcn_mfma_f32_16x16x32_bf16(
                    af[i][1], bf[j][1], acc[1][i][j], 0, 0, 0);
            }
        __builtin_amdgcn_s_setprio(0);

        if (st) { asm volatile("s_waitcnt vmcnt(2)" ::: "memory"); }
        else    { asm volatile("s_waitcnt vmcnt(0)" ::: "memory"); }
        __builtin_amdgcn_s_barrier();
    }

    // ---- epilogue
    float bv[4];
#pragma unroll
    for (int j = 0; j < 4; ++j)
        bv[j] = bias[bn*128 + cw*64 + j*16 + m16];

    if (QKV_MODE) {
        const int seg = bn >> 3;           // 0=Q(scaled), 1=K, 2=V(transposed)
        if (seg < 2) {
            bf16* Cout = (bf16*)(seg ? C1 : C0);
            const float sc = seg ? 1.0f : SCALE_Q;
#pragma unroll
            for (int q = 0; q < 2; ++q)
#pragma unroll
                for (int i = 0; i < 2; ++i)
#pragma unroll
                    for (int r = 0; r < 4; ++r) {
                        const int gm = bm*256 + q*128 + rw*32 + i*16 + quad*4 + r;
#pragma unroll
                        for (int j = 0; j < 4; ++j) {
                            const int cc = ((bn & 7)*128 + cw*64 + j*16 + m16);
                            Cout[(size_t)gm*DMODEL + cc] =
                                __float2bfloat16((acc[q][i][j][r] + bv[j]) * sc);
                        }
                    }
        } else {
            bf16* VT = (bf16*)C2;
#pragma unroll
            for (int q = 0; q < 2; ++q)
#pragma unroll
                for (int i = 0; i < 2; ++i) {
                    const int gm0 = bm*256 + q*128 + rw*32 + i*16 + quad*4;
                    const int bb = gm0 >> 11, t0 = gm0 & 2047;
#pragma unroll
                    for (int j = 0; j < 4; ++j) {
                        const int cv = (bn & 7)*128 + cw*64 + j*16 + m16;
                        const int hh = cv >> 6, dd = cv & 63;
                        union { unsigned long long u8; unsigned short us[4]; } o;
#pragma unroll
                        for (int r = 0; r < 4; ++r)
                            o.us[r] = f2bf_rne(acc[q][i][j][r] + bv[j]);
                        *(unsigned long long*)(VT
                            + ((size_t)((bb*NHEADS + hh)*DHEAD + dd))*SEQ + t0) = o.u8;
                    }
                }
        }
    } else {
        float* Cout = (float*)C0;
#pragma unroll
        for (int q = 0; q < 2; ++q)
#pragma unroll
            for (int i = 0; i < 2; ++i)
#pragma unroll
                for (int r = 0; r < 4; ++r) {
                    const int gm = bm*256 + q*128 + rw*32 + i*16 + quad*4 + r;
#pragma unroll
                    for (int j = 0; j < 4; ++j) {
                        const int cc = bn*128 + cw*64 + j*16 + m16;
                        Cout[(size_t)gm*DMODEL + cc] = acc[q][i][j][r] + bv[j];
                    }
                }
    }
}

// Distinct names so rocprof reports them separately
__global__ __launch_bounds__(512, 2) void qkv_proj(
    const float* __restrict__ bias, bf16* Q, bf16* K, bf16* VT)
{
    gemm_body<1>(nullptr, bias, Q, K, VT);
}
__global__ __launch_bounds__(512, 2) void out_proj(
    const void* __restrict__ Av, const float* __restrict__ bias, float* C)
{
    gemm_body<0>(Av, bias, C, nullptr, nullptr);
}

// ---------------------------------------------------------------------------
// MFMA flash attention v4 — transposed formulation, register-resident P.
// S^T = K·Q^T with C-init = -mrow (running max folded into the MFMA).
// P stays in registers: since sum_k P[k]V[k] is permutation-invariant in k,
// the key-slot permutation kappa(c,quad,j) = (c+2*(j>>2))*16 + quad*4 + (j&3)
// makes the PV B-fragment lane-local (lane holds exactly its own 16 P vals),
// and V is stored kappa-permuted at staging (8B-granular scatter from regs).
// No Ps LDS buffer -> 36.9KB LDS/block -> up to 4 blocks/CU.
// Defer-max (THR=8 base-2): common path has no rescale and no per-elem sub.
// ---------------------------------------------------------------------------
__global__ __launch_bounds__(256, 3) void attn_mfma4(
    const bf16* __restrict__ Qg, const bf16* __restrict__ Kg,
    const bf16* __restrict__ VTg, bf16* __restrict__ Og)
{
    __shared__ alignas(16) unsigned short Kt[2][64][72];   // [buf][key][d]
    __shared__ alignas(16) unsigned short Vt[2][64][72];   // [buf][d][key-slot]

    // XCD swizzle: 8 p-blocks of one (b,h) share an XCD -> K/V L2-resident
    const int x = blockIdx.x;
    const int hlo = x & 7, rest = x >> 3;
    const int p = rest & 7, t2 = rest >> 3;
    const int b = t2 >> 1, h = hlo | ((t2 & 1) << 3);

    const int tid = threadIdx.x;
    const int w = tid >> 6, lane = tid & 63;
    const int m16 = lane & 15, quad = lane >> 4;
    const int sr = tid >> 2, sc0 = (tid & 3) * 8;
    const size_t bh = (size_t)(b*NHEADS + h);
    (void)w;

    // kappa-scatter of 8 V values (keys kb..kb+7 of row vrow) into slot space
    auto vscat = [&](unsigned short* vrow, int kb, uint4 v) {
        int t4 = kb >> 4, qk = (kb >> 2) & 3;
        int s4 = (t4 & 1)*8 + qk*2 + (t4 >> 1);
        *(unsigned long long*)(vrow + s4*4) =
            ((unsigned long long)v.y << 32) | v.x;
        t4 = (kb + 4) >> 4; qk = ((kb + 4) >> 2) & 3;
        s4 = (t4 & 1)*8 + qk*2 + (t4 >> 1);
        *(unsigned long long*)(vrow + s4*4) =
            ((unsigned long long)v.w << 32) | v.z;
    };

    for (int seg = 0; seg < 2; ++seg) {
        const int qt  = seg ? (15 - p) : p;
        const int nkt = 2*qt + 2;
        const int qrow0 = qt*128 + w*32;

        short8 qf[2][2];
#pragma unroll
        for (int i = 0; i < 2; ++i)
#pragma unroll
            for (int c = 0; c < 2; ++c)
                qf[i][c] = *(const short8*)(Qg + (size_t)(b*SEQ + qrow0 + i*16 + m16)*DMODEL
                                            + h*DHEAD + c*32 + quad*8);

        floatx4 of[2][4];
        float mrow[2], lrow[2];
#pragma unroll
        for (int i = 0; i < 2; ++i) {
            mrow[i] = 0.f; lrow[i] = 0.f;
#pragma unroll
            for (int nt = 0; nt < 4; ++nt) { of[i][nt][0]=0.f; of[i][nt][1]=0.f; of[i][nt][2]=0.f; of[i][nt][3]=0.f; }
        }

        // ---- stage tile 0 into buf 0 (V kappa-permuted)
        {
            const bf16* kp = Kg  + (size_t)(b*SEQ + sr)*DMODEL + h*DHEAD + sc0;
            const bf16* vp = VTg + (bh*DHEAD + sr)*SEQ + sc0;
            const uint4 a0 = *(const uint4*)kp, a1 = *(const uint4*)(kp + 32);
            const uint4 b0 = *(const uint4*)vp, b1 = *(const uint4*)(vp + 32);
            __syncthreads();
            *(uint4*)&Kt[0][sr][sc0]      = a0;
            *(uint4*)&Kt[0][sr][sc0 + 32] = a1;
            vscat(&Vt[0][sr][0], sc0,      b0);
            vscat(&Vt[0][sr][0], sc0 + 32, b1);
            __syncthreads();
        }

        for (int kt = 0; kt < nkt; ++kt) {
            const int buf = kt & 1;
            const int k064 = kt * 64;
            const bool pre = (kt + 1 < nkt);
            uint4 kr0, kr1, vr0, vr1;
            if (pre) {
                const bf16* kp = Kg  + (size_t)(b*SEQ + k064 + 64 + sr)*DMODEL + h*DHEAD + sc0;
                const bf16* vp = VTg + (bh*DHEAD + sr)*SEQ + k064 + 64 + sc0;
                kr0 = *(const uint4*)kp; kr1 = *(const uint4*)(kp + 32);
                vr0 = *(const uint4*)vp; vr1 = *(const uint4*)(vp + 32);
            }

            // ---- S^T = K Q^T (16 MFMA), C-init = -mrow
            floatx4 sf[2][4];
            __builtin_amdgcn_s_setprio(1);
#pragma unroll
            for (int t4 = 0; t4 < 4; ++t4) {
                const short8 kf0 = *(const short8*)&Kt[buf][t4*16 + m16][quad*8];
                const short8 kf1 = *(const short8*)&Kt[buf][t4*16 + m16][32 + quad*8];
#pragma unroll
                for (int i = 0; i < 2; ++i) {
                    floatx4 a;
                    a[0] = -mrow[i]; a[1] = -mrow[i]; a[2] = -mrow[i]; a[3] = -mrow[i];
                    a = __builtin_amdgcn_mfma_f32_16x16x32_bf16(kf0, qf[i][0], a, 0, 0, 0);
                    a = __builtin_amdgcn_mfma_f32_16x16x32_bf16(kf1, qf[i][1], a, 0, 0, 0);
                    sf[i][t4] = a;
                }
            }
            __builtin_amdgcn_s_setprio(0);

            // ---- online softmax (per lane = per q-column), defer-max
            const bool need_mask = (k064 + 63 > qrow0);
            short8 pf[2][2];
#pragma unroll
            for (int i = 0; i < 2; ++i) {
                if (need_mask) {
                    const int qg = qrow0 + i*16 + m16;
#pragma unroll
                    for (int t4 = 0; t4 < 4; ++t4)
#pragma unroll
                        for (int r = 0; r < 4; ++r)
                            if (k064 + t4*16 + quad*4 + r > qg) sf[i][t4][r] = NEG_BIG;
                }
                float mx = sf[i][0][0];
#pragma unroll
                for (int t4 = 0; t4 < 4; ++t4)
#pragma unroll
                    for (int r = 0; r < 4; ++r) mx = fmaxf(mx, sf[i][t4][r]);
                mx = fmaxf(mx, __shfl_xor(mx, 16));
                mx = fmaxf(mx, __shfl_xor(mx, 32));

                float rs = 0.f;
                if (__any(mx > 8.f)) {
                    const float d     = fmaxf(mx, 0.f);
                    const float alpha = exp2f(-d);
                    mrow[i] += d;
                    lrow[i] *= alpha;
#pragma unroll
                    for (int nt = 0; nt < 4; ++nt)
#pragma unroll
                        for (int r = 0; r < 4; ++r) of[i][nt][r] *= alpha;
#pragma unroll
                    for (int t4 = 0; t4 < 4; ++t4)
#pragma unroll
                        for (int r = 0; r < 4; ++r) {
                            const float pv = exp2f(sf[i][t4][r] - d);
                            sf[i][t4][r] = pv;
                            rs += pv;
                        }
                } else {
#pragma unroll
                    for (int t4 = 0; t4 < 4; ++t4)
#pragma unroll
                        for (int r = 0; r < 4; ++r) {
                            const float pv = exp2f(sf[i][t4][r]);
                            sf[i][t4][r] = pv;
                            rs += pv;
                        }
                }
                rs += __shfl_xor(rs, 16);
                rs += __shfl_xor(rs, 32);
                lrow[i] += rs;

                // pack P to bf16 in-register; kappa makes the B-frag lane-local
                unsigned pw[4][2];
#pragma unroll
                for (int t4 = 0; t4 < 4; ++t4) {
                    pw[t4][0] = ((unsigned)f2bf_rne(sf[i][t4][1]) << 16) | f2bf_rne(sf[i][t4][0]);
                    pw[t4][1] = ((unsigned)f2bf_rne(sf[i][t4][3]) << 16) | f2bf_rne(sf[i][t4][2]);
                }
#pragma unroll
                for (int c = 0; c < 2; ++c) {
                    union { unsigned u[4]; short8 s8; } tu;
                    tu.u[0] = pw[c][0];     tu.u[1] = pw[c][1];
                    tu.u[2] = pw[c + 2][0]; tu.u[3] = pw[c + 2][1];
                    pf[i][c] = tu.s8;
                }
            }

            // ---- O^T += V^T P^T (16 MFMA); V already kappa-permuted
            __builtin_amdgcn_s_setprio(1);
#pragma unroll
            for (int nt = 0; nt < 4; ++nt) {
                const short8 vf0 = *(const short8*)&Vt[buf][nt*16 + m16][quad*8];
                const short8 vf1 = *(const short8*)&Vt[buf][nt*16 + m16][32 + quad*8];
#pragma unroll
                for (int i = 0; i < 2; ++i) {
                    of[i][nt] = __builtin_amdgcn_mfma_f32_16x16x32_bf16(vf0, pf[i][0], of[i][nt], 0, 0, 0);
                    of[i][nt] = __builtin_amdgcn_mfma_f32_16x16x32_bf16(vf1, pf[i][1], of[i][nt], 0, 0, 0);
                }
            }
            __builtin_amdgcn_s_setprio(0);

            if (pre) {
                *(uint4*)&Kt[buf^1][sr][sc0]      = kr0;
                *(uint4*)&Kt[buf^1][sr][sc0 + 32] = kr1;
                vscat(&Vt[buf^1][sr][0], sc0,      vr0);
                vscat(&Vt[buf^1][sr][0], sc0 + 32, vr1);
            }
            __syncthreads();
        }

        // ---- normalize + store O: lane owns row q, dims nt*16+quad*4+{0..3}
#pragma unroll
        for (int i = 0; i < 2; ++i) {
            const float rl = 1.f / fmaxf(lrow[i], 1e-20f);
            const size_t rowbase = (size_t)(b*SEQ + qrow0 + i*16 + m16)*DMODEL + h*DHEAD;
#pragma unroll
            for (int nt = 0; nt < 4; ++nt) {
                union { unsigned long long u8; unsigned short us[4]; } o;
#pragma unroll
                for (int r = 0; r < 4; ++r) o.us[r] = f2bf_rne(of[i][nt][r] * rl);
                *(unsigned long long*)(Og + rowbase + nt*16 + quad*4) = o.u8;
            }
        }
    }
}

__global__ void diag_fill(float* out, int n, float val) {
    int i = blockIdx.x*blockDim.x + threadIdx.x;
    if (i < n) out[i] = val;
}

// ---------------------------------------------------------------------------
extern "C" void kernel_launch(void* const* d_in, const int* in_sizes, int n_in,
                              void* d_out, int out_size, void* d_ws, size_t ws_size,
                              hipStream_t stream) {
    const float* x     = (const float*)d_in[0];
    const float* W_qkv = (const float*)d_in[1];
    const float* b_qkv = (const float*)d_in[2];
    const float* W_out = (const float*)d_in[3];
    const float* b_out = (const float*)d_in[4];

    if (ws_size < WS_NEED) {
        const float val = 100.f + (float)(ws_size >> 20);
        diag_fill<<<(out_size + 255)/256, 256, 0, stream>>>((float*)d_out, out_size, val);
        return;
    }

    bf16* Qb  = (bf16*)d_out;                                // d_out lo: Q (pre-scaled)
    bf16* VTb = (bf16*)d_out + (size_t)MROWS*DMODEL;         // d_out hi: VT
    bf16* Kb  = (bf16*)d_ws;                                 // ws lo: K
    bf16* Ob  = (bf16*)d_ws + (size_t)MROWS*DMODEL;          // ws hi: O

    // 0) casts
    cast_x<<<MROWS*DMODEL/2048, 256, 0, stream>>>(x);
    {
        dim3 gq(QKV_N/64, DMODEL/64);
        transcast_w<<<gq, 256, 0, stream>>>(W_qkv, QKV_N, 0);
        dim3 go(DMODEL/64, DMODEL/64);
        transcast_w<<<go, 256, 0, stream>>>(W_out, DMODEL, 1);
    }
    // 1) fused QKV projection; Q pre-scaled; V pre-transposed
    qkv_proj<<<768, 512, 0, stream>>>(b_qkv, Qb, Kb, VTb);
    // 2) flash attention v4 (register-resident P, 4 blocks/CU)
    attn_mfma4<<<512, 256, 0, stream>>>(Qb, Kb, VTb, Ob);
    // 3) output projection: O bf16 -> fp32 d_out
    out_proj<<<256, 512, 0, stream>>>(Ob, b_out, (float*)d_out);
}

// Round 6
// 287.926 us; speedup vs baseline: 1.0486x; 1.0486x over previous
//
#include <hip/hip_runtime.h>
#include <hip/hip_bf16.h>

#define BATCH   4
#define SEQ     2048
#define DMODEL  1024
#define NHEADS  16
#define DHEAD   64
#define MROWS   (BATCH*SEQ)        // 8192
#define QKV_N   (3*DMODEL)         // 3072
#define NEG_BIG (-1.0e30f)
#define WS_NEED ((size_t)MROWS * 2*DMODEL * sizeof(__hip_bfloat16))  // 33,554,432
#define SCALE_Q 0.18033688011112042f   // 0.125 * log2(e); folded into Q at projection

using bf16 = __hip_bfloat16;
typedef __attribute__((ext_vector_type(8))) short short8;
typedef __attribute__((ext_vector_type(4))) float floatx4;

// Static device buffers (module BSS; no hipMalloc)
__device__ __align__(16) unsigned short g_wqT[QKV_N * DMODEL];   // W_qkv^T bf16
__device__ __align__(16) unsigned short g_woT[DMODEL * DMODEL];  // W_out^T bf16
__device__ __align__(16) unsigned short g_xb [MROWS * DMODEL];   // x bf16

__device__ __forceinline__ unsigned short f2bf_rne(float f) {
    union { bf16 b; unsigned short u; } t;
    t.b = __float2bfloat16(f);
    return t.u;
}

// async global->LDS, 16B per lane; LDS dest = wave-uniform base + lane*16
__device__ __forceinline__ void gload_lds16(const void* g, void* l) {
    __builtin_amdgcn_global_load_lds(
        (const __attribute__((address_space(1))) unsigned*)g,
        (__attribute__((address_space(3))) unsigned*)l, 16, 0, 0);
}

// ---------------------------------------------------------------------------
// x fp32 -> bf16
// ---------------------------------------------------------------------------
__global__ __launch_bounds__(256) void cast_x(const float* __restrict__ x) {
    const size_t i = ((size_t)blockIdx.x*256 + threadIdx.x)*8;
    const float4 a = *(const float4*)(x + i);
    const float4 b = *(const float4*)(x + i + 4);
    union { uint4 u4; unsigned short us[8]; } o;
    o.us[0]=f2bf_rne(a.x); o.us[1]=f2bf_rne(a.y); o.us[2]=f2bf_rne(a.z); o.us[3]=f2bf_rne(a.w);
    o.us[4]=f2bf_rne(b.x); o.us[5]=f2bf_rne(b.y); o.us[6]=f2bf_rne(b.z); o.us[7]=f2bf_rne(b.w);
    *(uint4*)(g_xb + i) = o.u4;
}

// ---------------------------------------------------------------------------
// Weight transpose + cast (both weights in ONE launch):
// blocks [0,48): W_qkv fp32 [1024][3072] -> g_wqT [3072][1024]
// blocks [48,64): W_out fp32 [1024][1024] -> g_woT [1024][1024]
// ---------------------------------------------------------------------------
__global__ __launch_bounds__(256) void transcast_w2(
    const float* __restrict__ Wq, const float* __restrict__ Wo)
{
    const int bx = blockIdx.x;
    const float* W;
    unsigned short* dst;
    int N, n0;
    if (bx < 48) { W = Wq; dst = g_wqT; N = QKV_N;  n0 = bx * 64; }
    else         { W = Wo; dst = g_woT; N = DMODEL; n0 = (bx - 48) * 64; }
    const int k0 = blockIdx.y * 64;

    __shared__ unsigned short T[64][72];
    const int tid = threadIdx.x;
    const int r = tid >> 2, c0 = (tid & 3) * 16;

#pragma unroll
    for (int it = 0; it < 4; ++it) {
        const float4 v = *(const float4*)(W + (size_t)(k0 + r)*N + n0 + c0 + it*4);
        T[r][c0 + it*4 + 0] = f2bf_rne(v.x);
        T[r][c0 + it*4 + 1] = f2bf_rne(v.y);
        T[r][c0 + it*4 + 2] = f2bf_rne(v.z);
        T[r][c0 + it*4 + 3] = f2bf_rne(v.w);
    }
    __syncthreads();
    const int nr = tid >> 2, kc0 = (tid & 3) * 16;
#pragma unroll
    for (int it = 0; it < 2; ++it) {
        union { uint4 u4; unsigned short us[8]; } o;
#pragma unroll
        for (int j = 0; j < 8; j++) o.us[j] = T[kc0 + it*8 + j][nr];
        *(uint4*)(dst + (size_t)(n0 + nr)*DMODEL + k0 + kc0 + it*8) = o.u4;
    }
}

// ---------------------------------------------------------------------------
// 256x128 BK=64 phase-pipelined MFMA GEMM body (shared by qkv_proj/out_proj).
// 8 waves (512 thr), wave grid 4M x 2N, per-wave output 64x64.
// LDS 96 KiB: A 2buf x 32KB (32 subtiles), B 2buf x 16KB (16 subtiles).
// Subtile = 16 rows x 32 k x 2B = 1KB; 16B chunk c of row r at slot
// c ^ ((r>>1)&3) -> frag ds_read_b128 conflict-free.
// Phase schedule per K-tile t (stage tile t+1 into buf^1):
//  p0: read bf[4][2]+af(qm0); stage B'0,B'1,A'0,A'1; bar; 16 MFMA;
//      vmcnt(4) [drains A(t)2,A(t)3 - issued one tile ago]; bar
//  p1: read af(qm1);          stage A'2,A'3;          bar; 16 MFMA;
//      vmcnt(2) [drains B'0,B'1,A'0,A'1 - issued one phase ago]; bar
// No wait ever targets a load issued in the same phase.
// ---------------------------------------------------------------------------
template<int QKV_MODE>
__device__ __forceinline__ void gemm_body(
    const void* __restrict__ Av, const float* __restrict__ bias,
    void* __restrict__ C0, void* __restrict__ C1, void* __restrict__ C2)
{
    const unsigned short* A  = QKV_MODE ? g_xb  : (const unsigned short*)Av;
    const unsigned short* BT = QKV_MODE ? g_wqT : g_woT;
    constexpr int NBN = QKV_MODE ? 24 : 8;      // N/128
    constexpr int NWG = NBN * 32;               // * (M/256)

    __shared__ __align__(16) char smem[98304];  // A: 2x32KB @0; B: 2x16KB @65536
    char* const sA = smem;
    char* const sB = smem + 65536;

    // XCD-aware bijective swizzle: consecutive hw blocks on one XCD sweep bn
    const int orig = blockIdx.x;
    const int wgid = (orig & 7) * (NWG >> 3) + (orig >> 3);
    const int bm = wgid / NBN, bn = wgid % NBN;

    const int tid  = threadIdx.x;
    const int w    = tid >> 6, lane = tid & 63;
    const int m16  = lane & 15, quad = lane >> 4;
    const int rw   = w >> 1, cw = w & 1;

    // staging lane decomposition: slot chunk (r,c) holds data chunk c^((r>>1)&3)
    const int rL = lane >> 2;
    const int cD = (lane & 3) ^ ((lane >> 3) & 3);
    const unsigned short* gA = A  + (size_t)(bm*256 + rL)*DMODEL + cD*8;
    const unsigned short* gB = BT + (size_t)(bn*128 + rL)*DMODEL + cD*8;

    // frag-read lane offset (swizzled)
    const int laneRd = m16*64 + (quad ^ ((m16 >> 1) & 3))*16;

    floatx4 acc[2][2][4];   // [qm][i][j]
#pragma unroll
    for (int q = 0; q < 2; ++q)
#pragma unroll
        for (int i = 0; i < 2; ++i)
#pragma unroll
            for (int j = 0; j < 4; ++j) {
                acc[q][i][j][0]=0.f; acc[q][i][j][1]=0.f;
                acc[q][i][j][2]=0.f; acc[q][i][j][3]=0.f;
            }

    // A round a (0..3): wave w stages subtile (rg=4a+(w>>1), kh=w&1)
    auto stageA = [&](int buf, int a, int k0) {
        const int rg = 4*a + (w >> 1), kh = w & 1;
        gload_lds16(gA + (size_t)(rg*16)*DMODEL + k0 + kh*32,
                    sA + buf*32768 + (rg*2 + kh)*1024);
    };
    // B round b (0..1): wave w stages subtile (rg=4b+(w>>1), kh=w&1)
    auto stageB = [&](int buf, int b, int k0) {
        const int rg = 4*b + (w >> 1), kh = w & 1;
        gload_lds16(gB + (size_t)(rg*16)*DMODEL + k0 + kh*32,
                    sB + buf*16384 + (rg*2 + kh)*1024);
    };

    // ---- prologue: tile 0 -> buf 0
    stageB(0, 0, 0); stageB(0, 1, 0);
    stageA(0, 0, 0); stageA(0, 1, 0); stageA(0, 2, 0); stageA(0, 3, 0);
    asm volatile("s_waitcnt vmcnt(0)" ::: "memory");
    __builtin_amdgcn_s_barrier();

    const int NT = DMODEL / 64;   // 16
    for (int t = 0; t < NT; ++t) {
        const int  buf = t & 1;
        const int  k1  = (t + 1) * 64;
        const bool st  = (t + 1 < NT);
        char* const Ab = sA + buf*32768;
        char* const Bb = sB + buf*16384;

        // ================= phase 0: qm = 0 =================
        short8 bf[4][2], af[2][2];
#pragma unroll
        for (int j = 0; j < 4; ++j)
#pragma unroll
            for (int kh = 0; kh < 2; ++kh)
                bf[j][kh] = *(const short8*)(Bb + ((cw*4 + j)*2 + kh)*1024 + laneRd);
#pragma unroll
        for (int i = 0; i < 2; ++i)
#pragma unroll
            for (int kh = 0; kh < 2; ++kh)
                af[i][kh] = *(const short8*)(Ab + ((rw*2 + i)*2 + kh)*1024 + laneRd);

        if (st) { stageB(buf^1, 0, k1); stageB(buf^1, 1, k1);
                  stageA(buf^1, 0, k1); stageA(buf^1, 1, k1); }
        __builtin_amdgcn_s_barrier();

        __builtin_amdgcn_s_setprio(1);
#pragma unroll
        for (int i = 0; i < 2; ++i)
#pragma unroll
            for (int j = 0; j < 4; ++j) {
                acc[0][i][j] = __builtin_amdgcn_mfma_f32_16x16x32_bf16(
                    af[i][0], bf[j][0], acc[0][i][j], 0, 0, 0);
                acc[0][i][j] = __builtin_amdgcn_mfma_f32_16x16x32_bf16(
                    af[i][1], bf[j][1], acc[0][i][j], 0, 0, 0);
            }
        __builtin_amdgcn_s_setprio(0);

        if (st) { asm volatile("s_waitcnt vmcnt(4)" ::: "memory"); }
        else    { asm volatile("s_waitcnt vmcnt(0)" ::: "memory"); }
        __builtin_amdgcn_s_barrier();

        // ================= phase 1: qm = 1 =================
#pragma unroll
        for (int i = 0; i < 2; ++i)
#pragma unroll
            for (int kh = 0; kh < 2; ++kh)
                af[i][kh] = *(const short8*)(Ab + ((8 + rw*2 + i)*2 + kh)*1024 + laneRd);

        if (st) { stageA(buf^1, 2, k1); stageA(buf^1, 3, k1); }
        __builtin_amdgcn_s_barrier();

        __builtin_amdgcn_s_setprio(1);
#pragma unroll
        for (int i = 0; i < 2; ++i)
#pragma unroll
            for (int j = 0; j < 4; ++j) {
                acc[1][i][j] = __builtin_amdgcn_mfma_f32_16x16x32_bf16(
                    af[i][0], bf[j][0], acc[1][i][j], 0, 0, 0);
                acc[1][i][j] = __builtin_amdgcn_mfma_f32_16x16x32_bf16(
                    af[i][1], bf[j][1], acc[1][i][j], 0, 0, 0);
            }
        __builtin_amdgcn_s_setprio(0);

        if (st) { asm volatile("s_waitcnt vmcnt(2)" ::: "memory"); }
        else    { asm volatile("s_waitcnt vmcnt(0)" ::: "memory"); }
        __builtin_amdgcn_s_barrier();
    }

    // ---- epilogue
    float bv[4];
#pragma unroll
    for (int j = 0; j < 4; ++j)
        bv[j] = bias[bn*128 + cw*64 + j*16 + m16];

    if (QKV_MODE) {
        const int seg = bn >> 3;           // 0=Q(scaled), 1=K, 2=V(transposed)
        if (seg < 2) {
            bf16* Cout = (bf16*)(seg ? C1 : C0);
            const float sc = seg ? 1.0f : SCALE_Q;
#pragma unroll
            for (int q = 0; q < 2; ++q)
#pragma unroll
                for (int i = 0; i < 2; ++i)
#pragma unroll
                    for (int r = 0; r < 4; ++r) {
                        const int gm = bm*256 + q*128 + rw*32 + i*16 + quad*4 + r;
#pragma unroll
                        for (int j = 0; j < 4; ++j) {
                            const int cc = ((bn & 7)*128 + cw*64 + j*16 + m16);
                            Cout[(size_t)gm*DMODEL + cc] =
                                __float2bfloat16((acc[q][i][j][r] + bv[j]) * sc);
                        }
                    }
        } else {
            bf16* VT = (bf16*)C2;
#pragma unroll
            for (int q = 0; q < 2; ++q)
#pragma unroll
                for (int i = 0; i < 2; ++i) {
                    const int gm0 = bm*256 + q*128 + rw*32 + i*16 + quad*4;
                    const int bb = gm0 >> 11, t0 = gm0 & 2047;
#pragma unroll
                    for (int j = 0; j < 4; ++j) {
                        const int cv = (bn & 7)*128 + cw*64 + j*16 + m16;
                        const int hh = cv >> 6, dd = cv & 63;
                        union { unsigned long long u8; unsigned short us[4]; } o;
#pragma unroll
                        for (int r = 0; r < 4; ++r)
                            o.us[r] = f2bf_rne(acc[q][i][j][r] + bv[j]);
                        *(unsigned long long*)(VT
                            + ((size_t)((bb*NHEADS + hh)*DHEAD + dd))*SEQ + t0) = o.u8;
                    }
                }
        }
    } else {
        float* Cout = (float*)C0;
#pragma unroll
        for (int q = 0; q < 2; ++q)
#pragma unroll
            for (int i = 0; i < 2; ++i)
#pragma unroll
                for (int r = 0; r < 4; ++r) {
                    const int gm = bm*256 + q*128 + rw*32 + i*16 + quad*4 + r;
#pragma unroll
                    for (int j = 0; j < 4; ++j) {
                        const int cc = bn*128 + cw*64 + j*16 + m16;
                        Cout[(size_t)gm*DMODEL + cc] = acc[q][i][j][r] + bv[j];
                    }
                }
    }
}

// Distinct names so rocprof reports them separately
__global__ __launch_bounds__(512, 2) void qkv_proj(
    const float* __restrict__ bias, bf16* Q, bf16* K, bf16* VT)
{
    gemm_body<1>(nullptr, bias, Q, K, VT);
}
__global__ __launch_bounds__(512, 2) void out_proj(
    const void* __restrict__ Av, const float* __restrict__ bias, float* C)
{
    gemm_body<0>(Av, bias, C, nullptr, nullptr);
}

// ---------------------------------------------------------------------------
// MFMA flash attention v5 — v3 structure (proven 92 us) + single-buffered V.
// S^T = K·Q^T and O^T = V^T·P^T via operand-swapped MFMAs; lane owns one
// q-column per i-group; Ps LDS round-trip for P (latency-tolerant, proven).
// V(t+1) is pre-loaded to registers early; its LDS write moves behind a
// barrier after PV -> V needs ONE buffer. LDS 55.3KB -> 45KB -> 3 blocks/CU
// (12 waves) vs 2: +50% latency hiding for this latency-bound kernel.
// Cost: one extra barrier per K-tile. No setprio (VALU-bound: it hurt in v4).
// ---------------------------------------------------------------------------
__global__ __launch_bounds__(256, 3) void attn_mfma5(
    const bf16* __restrict__ Qg, const bf16* __restrict__ Kg,
    const bf16* __restrict__ VTg, bf16* __restrict__ Og)
{
    __shared__ alignas(16) unsigned short Kt[2][64][72];   // [buf][key][d]
    __shared__ alignas(16) unsigned short Vt[64][72];      // [d][key] single buf
    __shared__ alignas(16) unsigned short Ps[4][32][72];   // [wave][q][key]

    // XCD swizzle: 8 p-blocks of one (b,h) share an XCD -> K/V L2-resident
    const int x = blockIdx.x;
    const int hlo = x & 7, rest = x >> 3;
    const int p = rest & 7, t2 = rest >> 3;
    const int b = t2 >> 1, h = hlo | ((t2 & 1) << 3);

    const int tid = threadIdx.x;
    const int w = tid >> 6, lane = tid & 63;
    const int m16 = lane & 15, quad = lane >> 4;
    const int sr = tid >> 2, sc0 = (tid & 3) * 8;
    const size_t bh = (size_t)(b*NHEADS + h);

    for (int seg = 0; seg < 2; ++seg) {
        const int qt  = seg ? (15 - p) : p;
        const int nkt = 2*qt + 2;
        const int qrow0 = qt*128 + w*32;

        short8 qf[2][2];
#pragma unroll
        for (int i = 0; i < 2; ++i)
#pragma unroll
            for (int c = 0; c < 2; ++c)
                qf[i][c] = *(const short8*)(Qg + (size_t)(b*SEQ + qrow0 + i*16 + m16)*DMODEL
                                            + h*DHEAD + c*32 + quad*8);

        floatx4 of[2][4];
        float mrow[2], lrow[2];
#pragma unroll
        for (int i = 0; i < 2; ++i) {
            mrow[i] = NEG_BIG; lrow[i] = 0.f;
#pragma unroll
            for (int nt = 0; nt < 4; ++nt) { of[i][nt][0]=0.f; of[i][nt][1]=0.f; of[i][nt][2]=0.f; of[i][nt][3]=0.f; }
        }

        // ---- stage tile 0
        {
            const bf16* kp = Kg  + (size_t)(b*SEQ + sr)*DMODEL + h*DHEAD + sc0;
            const bf16* vp = VTg + (bh*DHEAD + sr)*SEQ + sc0;
            const uint4 a0 = *(const uint4*)kp, a1 = *(const uint4*)(kp + 32);
            const uint4 b0 = *(const uint4*)vp, b1 = *(const uint4*)(vp + 32);
            __syncthreads();
            *(uint4*)&Kt[0][sr][sc0]      = a0;
            *(uint4*)&Kt[0][sr][sc0 + 32] = a1;
            *(uint4*)&Vt[sr][sc0]         = b0;
            *(uint4*)&Vt[sr][sc0 + 32]    = b1;
            __syncthreads();
        }

        for (int kt = 0; kt < nkt; ++kt) {
            const int buf = kt & 1;
            const int k064 = kt * 64;
            const bool pre = (kt + 1 < nkt);
            uint4 kr0, kr1, vr0, vr1;
            if (pre) {
                const bf16* kp = Kg  + (size_t)(b*SEQ + k064 + 64 + sr)*DMODEL + h*DHEAD + sc0;
                const bf16* vp = VTg + (bh*DHEAD + sr)*SEQ + k064 + 64 + sc0;
                kr0 = *(const uint4*)kp; kr1 = *(const uint4*)(kp + 32);
                vr0 = *(const uint4*)vp; vr1 = *(const uint4*)(vp + 32);
            }

            // ---- S^T = K Q^T (16 MFMA): rows=key(quad*4+r, t4), cols=q(m16)
            floatx4 sf[2][4];
#pragma unroll
            for (int t4 = 0; t4 < 4; ++t4) {
                const short8 kf0 = *(const short8*)&Kt[buf][t4*16 + m16][quad*8];
                const short8 kf1 = *(const short8*)&Kt[buf][t4*16 + m16][32 + quad*8];
#pragma unroll
                for (int i = 0; i < 2; ++i) {
                    floatx4 a; a[0]=0.f; a[1]=0.f; a[2]=0.f; a[3]=0.f;
                    a = __builtin_amdgcn_mfma_f32_16x16x32_bf16(kf0, qf[i][0], a, 0, 0, 0);
                    a = __builtin_amdgcn_mfma_f32_16x16x32_bf16(kf1, qf[i][1], a, 0, 0, 0);
                    sf[i][t4] = a;
                }
            }

            // ---- online softmax (per lane = per q-column), defer-max
            const bool need_mask = (k064 + 63 > qrow0);
#pragma unroll
            for (int i = 0; i < 2; ++i) {
                if (need_mask) {
                    const int qg = qrow0 + i*16 + m16;
#pragma unroll
                    for (int t4 = 0; t4 < 4; ++t4)
#pragma unroll
                        for (int r = 0; r < 4; ++r)
                            if (k064 + t4*16 + quad*4 + r > qg) sf[i][t4][r] = NEG_BIG;
                }
                float mx = sf[i][0][0];
#pragma unroll
                for (int t4 = 0; t4 < 4; ++t4)
#pragma unroll
                    for (int r = 0; r < 4; ++r) mx = fmaxf(mx, sf[i][t4][r]);
                mx = fmaxf(mx, __shfl_xor(mx, 16));
                mx = fmaxf(mx, __shfl_xor(mx, 32));

                // defer-max: only rescale when the tile max meaningfully grows.
                // S is in base-2 log units; THR=8 bounds P by 2^8=256 (safe).
                if (__any(mx > mrow[i] + 8.f)) {
                    const float mnew  = fmaxf(mrow[i], mx);
                    const float alpha = exp2f(mrow[i] - mnew);
                    mrow[i] = mnew;
                    lrow[i] *= alpha;
#pragma unroll
                    for (int nt = 0; nt < 4; ++nt)
#pragma unroll
                        for (int r = 0; r < 4; ++r) of[i][nt][r] *= alpha;
                }

                float rs = 0.f;
#pragma unroll
                for (int t4 = 0; t4 < 4; ++t4) {
#pragma unroll
                    for (int r = 0; r < 4; ++r) {
                        const float pv = exp2f(sf[i][t4][r] - mrow[i]);
                        sf[i][t4][r] = pv;
                        rs += pv;
                    }
                }
                rs += __shfl_xor(rs, 16);
                rs += __shfl_xor(rs, 32);
                lrow[i] += rs;

                // P^T -> LDS: 4 consecutive keys per b64 store
#pragma unroll
                for (int t4 = 0; t4 < 4; ++t4) {
                    union { unsigned long long u8; unsigned short us[4]; } o;
#pragma unroll
                    for (int r = 0; r < 4; ++r) o.us[r] = f2bf_rne(sf[i][t4][r]);
                    *(unsigned long long*)&Ps[w][i*16 + m16][t4*16 + quad*4] = o.u8;
                }
            }

            // ---- O^T += V^T P^T (16 MFMA); Ps wave-local, Vt single-buf
            short8 pf[2][2];
#pragma unroll
            for (int i = 0; i < 2; ++i)
#pragma unroll
                for (int c = 0; c < 2; ++c)
                    pf[i][c] = *(const short8*)&Ps[w][i*16 + m16][c*32 + quad*8];
#pragma unroll
            for (int nt = 0; nt < 4; ++nt) {
                const short8 vf0 = *(const short8*)&Vt[nt*16 + m16][quad*8];
                const short8 vf1 = *(const short8*)&Vt[nt*16 + m16][32 + quad*8];
#pragma unroll
                for (int i = 0; i < 2; ++i) {
                    of[i][nt] = __builtin_amdgcn_mfma_f32_16x16x32_bf16(vf0, pf[i][0], of[i][nt], 0, 0, 0);
                    of[i][nt] = __builtin_amdgcn_mfma_f32_16x16x32_bf16(vf1, pf[i][1], of[i][nt], 0, 0, 0);
                }
            }

            // all waves done reading Vt before it is overwritten
            __syncthreads();
            if (pre) {
                *(uint4*)&Kt[buf^1][sr][sc0]      = kr0;
                *(uint4*)&Kt[buf^1][sr][sc0 + 32] = kr1;
                *(uint4*)&Vt[sr][sc0]             = vr0;
                *(uint4*)&Vt[sr][sc0 + 32]        = vr1;
            }
            __syncthreads();
        }

        // ---- normalize + store O: lane owns row q, dims nt*16+quad*4+{0..3}
#pragma unroll
        for (int i = 0; i < 2; ++i) {
            const float rl = 1.f / fmaxf(lrow[i], 1e-20f);
            const size_t rowbase = (size_t)(b*SEQ + qrow0 + i*16 + m16)*DMODEL + h*DHEAD;
#pragma unroll
            for (int nt = 0; nt < 4; ++nt) {
                union { unsigned long long u8; unsigned short us[4]; } o;
#pragma unroll
                for (int r = 0; r < 4; ++r) o.us[r] = f2bf_rne(of[i][nt][r] * rl);
                *(unsigned long long*)(Og + rowbase + nt*16 + quad*4) = o.u8;
            }
        }
    }
}

__global__ void diag_fill(float* out, int n, float val) {
    int i = blockIdx.x*blockDim.x + threadIdx.x;
    if (i < n) out[i] = val;
}

// ---------------------------------------------------------------------------
extern "C" void kernel_launch(void* const* d_in, const int* in_sizes, int n_in,
                              void* d_out, int out_size, void* d_ws, size_t ws_size,
                              hipStream_t stream) {
    const float* x     = (const float*)d_in[0];
    const float* W_qkv = (const float*)d_in[1];
    const float* b_qkv = (const float*)d_in[2];
    const float* W_out = (const float*)d_in[3];
    const float* b_out = (const float*)d_in[4];

    if (ws_size < WS_NEED) {
        const float val = 100.f + (float)(ws_size >> 20);
        diag_fill<<<(out_size + 255)/256, 256, 0, stream>>>((float*)d_out, out_size, val);
        return;
    }

    bf16* Qb  = (bf16*)d_out;                                // d_out lo: Q (pre-scaled)
    bf16* VTb = (bf16*)d_out + (size_t)MROWS*DMODEL;         // d_out hi: VT
    bf16* Kb  = (bf16*)d_ws;                                 // ws lo: K
    bf16* Ob  = (bf16*)d_ws + (size_t)MROWS*DMODEL;          // ws hi: O

    // 0) casts (both weight transposes fused into one launch)
    cast_x<<<MROWS*DMODEL/2048, 256, 0, stream>>>(x);
    {
        dim3 g(64, DMODEL/64);
        transcast_w2<<<g, 256, 0, stream>>>(W_qkv, W_out);
    }
    // 1) fused QKV projection; Q pre-scaled; V pre-transposed
    qkv_proj<<<768, 512, 0, stream>>>(b_qkv, Qb, Kb, VTb);
    // 2) flash attention v5 (single-buffered V, 3 blocks/CU)
    attn_mfma5<<<512, 256, 0, stream>>>(Qb, Kb, VTb, Ob);
    // 3) output projection: O bf16 -> fp32 d_out
    out_proj<<<256, 512, 0, stream>>>(Ob, b_out, (float*)d_out);
}

// Round 8
// 269.436 us; speedup vs baseline: 1.1206x; 1.0686x over previous
//
#include <hip/hip_runtime.h>
#include <hip/hip_bf16.h>

#define BATCH   4
#define SEQ     2048
#define DMODEL  1024
#define NHEADS  16
#define DHEAD   64
#define MROWS   (BATCH*SEQ)        // 8192
#define QKV_N   (3*DMODEL)         // 3072
#define NEG_BIG (-1.0e30f)
#define WS_NEED ((size_t)MROWS * 2*DMODEL * sizeof(__hip_bfloat16))  // 33,554,432
#define SCALE_Q 0.18033688011112042f   // 0.125 * log2(e); folded into Q at projection

using bf16 = __hip_bfloat16;
typedef __attribute__((ext_vector_type(8))) short short8;
typedef __attribute__((ext_vector_type(4))) float floatx4;

// Static device buffers (module BSS; no hipMalloc)
__device__ __align__(16) unsigned short g_wqT[QKV_N * DMODEL];   // W_qkv^T bf16
__device__ __align__(16) unsigned short g_woT[DMODEL * DMODEL];  // W_out^T bf16
__device__ __align__(16) unsigned short g_xb [MROWS * DMODEL];   // x bf16

__device__ __forceinline__ unsigned short f2bf_rne(float f) {
    union { bf16 b; unsigned short u; } t;
    t.b = __float2bfloat16(f);
    return t.u;
}

// async global->LDS, 16B per lane; LDS dest = wave-uniform base + lane*16
__device__ __forceinline__ void gload_lds16(const void* g, void* l) {
    __builtin_amdgcn_global_load_lds(
        (const __attribute__((address_space(1))) unsigned*)g,
        (__attribute__((address_space(3))) unsigned*)l, 16, 0, 0);
}

// ---------------------------------------------------------------------------
// x fp32 -> bf16
// ---------------------------------------------------------------------------
__global__ __launch_bounds__(256) void cast_x(const float* __restrict__ x) {
    const size_t i = ((size_t)blockIdx.x*256 + threadIdx.x)*8;
    const float4 a = *(const float4*)(x + i);
    const float4 b = *(const float4*)(x + i + 4);
    union { uint4 u4; unsigned short us[8]; } o;
    o.us[0]=f2bf_rne(a.x); o.us[1]=f2bf_rne(a.y); o.us[2]=f2bf_rne(a.z); o.us[3]=f2bf_rne(a.w);
    o.us[4]=f2bf_rne(b.x); o.us[5]=f2bf_rne(b.y); o.us[6]=f2bf_rne(b.z); o.us[7]=f2bf_rne(b.w);
    *(uint4*)(g_xb + i) = o.u4;
}

// ---------------------------------------------------------------------------
// Weight transpose + cast (both weights in ONE launch):
// blocks [0,48): W_qkv fp32 [1024][3072] -> g_wqT [3072][1024]
// blocks [48,64): W_out fp32 [1024][1024] -> g_woT [1024][1024]
// ---------------------------------------------------------------------------
__global__ __launch_bounds__(256) void transcast_w2(
    const float* __restrict__ Wq, const float* __restrict__ Wo)
{
    const int bx = blockIdx.x;
    const float* W;
    unsigned short* dst;
    int N, n0;
    if (bx < 48) { W = Wq; dst = g_wqT; N = QKV_N;  n0 = bx * 64; }
    else         { W = Wo; dst = g_woT; N = DMODEL; n0 = (bx - 48) * 64; }
    const int k0 = blockIdx.y * 64;

    __shared__ unsigned short T[64][72];
    const int tid = threadIdx.x;
    const int r = tid >> 2, c0 = (tid & 3) * 16;

#pragma unroll
    for (int it = 0; it < 4; ++it) {
        const float4 v = *(const float4*)(W + (size_t)(k0 + r)*N + n0 + c0 + it*4);
        T[r][c0 + it*4 + 0] = f2bf_rne(v.x);
        T[r][c0 + it*4 + 1] = f2bf_rne(v.y);
        T[r][c0 + it*4 + 2] = f2bf_rne(v.z);
        T[r][c0 + it*4 + 3] = f2bf_rne(v.w);
    }
    __syncthreads();
    const int nr = tid >> 2, kc0 = (tid & 3) * 16;
#pragma unroll
    for (int it = 0; it < 2; ++it) {
        union { uint4 u4; unsigned short us[8]; } o;
#pragma unroll
        for (int j = 0; j < 8; j++) o.us[j] = T[kc0 + it*8 + j][nr];
        *(uint4*)(dst + (size_t)(n0 + nr)*DMODEL + k0 + kc0 + it*8) = o.u4;
    }
}

// ---------------------------------------------------------------------------
// 256x128 BK=64 phase-pipelined MFMA GEMM body (shared by qkv_proj/out_proj).
// 8 waves (512 thr), wave grid 4M x 2N, per-wave output 64x64.
// LDS 96 KiB: A 2buf x 32KB (32 subtiles), B 2buf x 16KB (16 subtiles).
// Subtile = 16 rows x 32 k x 2B = 1KB; 16B chunk c of row r at slot
// c ^ ((r>>1)&3) -> frag ds_read_b128 conflict-free.
// Phase schedule per K-tile t (stage tile t+1 into buf^1):
//  p0: read bf[4][2]+af(qm0); stage B'0,B'1,A'0,A'1; bar; 16 MFMA;
//      vmcnt(4) [drains A(t)2,A(t)3 - issued one tile ago]; bar
//  p1: read af(qm1);          stage A'2,A'3;          bar; 16 MFMA;
//      vmcnt(2) [drains B'0,B'1,A'0,A'1 - issued one phase ago]; bar
// No wait ever targets a load issued in the same phase.
// ---------------------------------------------------------------------------
template<int QKV_MODE>
__device__ __forceinline__ void gemm_body(
    const void* __restrict__ Av, const float* __restrict__ bias,
    void* __restrict__ C0, void* __restrict__ C1, void* __restrict__ C2)
{
    const unsigned short* A  = QKV_MODE ? g_xb  : (const unsigned short*)Av;
    const unsigned short* BT = QKV_MODE ? g_wqT : g_woT;
    constexpr int NBN = QKV_MODE ? 24 : 8;      // N/128
    constexpr int NWG = NBN * 32;               // * (M/256)

    __shared__ __align__(16) char smem[98304];  // A: 2x32KB @0; B: 2x16KB @65536
    char* const sA = smem;
    char* const sB = smem + 65536;

    // XCD-aware bijective swizzle: consecutive hw blocks on one XCD sweep bn
    const int orig = blockIdx.x;
    const int wgid = (orig & 7) * (NWG >> 3) + (orig >> 3);
    const int bm = wgid / NBN, bn = wgid % NBN;

    const int tid  = threadIdx.x;
    const int w    = tid >> 6, lane = tid & 63;
    const int m16  = lane & 15, quad = lane >> 4;
    const int rw   = w >> 1, cw = w & 1;

    // staging lane decomposition: slot chunk (r,c) holds data chunk c^((r>>1)&3)
    const int rL = lane >> 2;
    const int cD = (lane & 3) ^ ((lane >> 3) & 3);
    const unsigned short* gA = A  + (size_t)(bm*256 + rL)*DMODEL + cD*8;
    const unsigned short* gB = BT + (size_t)(bn*128 + rL)*DMODEL + cD*8;

    // frag-read lane offset (swizzled)
    const int laneRd = m16*64 + (quad ^ ((m16 >> 1) & 3))*16;

    floatx4 acc[2][2][4];   // [qm][i][j]
#pragma unroll
    for (int q = 0; q < 2; ++q)
#pragma unroll
        for (int i = 0; i < 2; ++i)
#pragma unroll
            for (int j = 0; j < 4; ++j) {
                acc[q][i][j][0]=0.f; acc[q][i][j][1]=0.f;
                acc[q][i][j][2]=0.f; acc[q][i][j][3]=0.f;
            }

    // A round a (0..3): wave w stages subtile (rg=4a+(w>>1), kh=w&1)
    auto stageA = [&](int buf, int a, int k0) {
        const int rg = 4*a + (w >> 1), kh = w & 1;
        gload_lds16(gA + (size_t)(rg*16)*DMODEL + k0 + kh*32,
                    sA + buf*32768 + (rg*2 + kh)*1024);
    };
    // B round b (0..1): wave w stages subtile (rg=4b+(w>>1), kh=w&1)
    auto stageB = [&](int buf, int b, int k0) {
        const int rg = 4*b + (w >> 1), kh = w & 1;
        gload_lds16(gB + (size_t)(rg*16)*DMODEL + k0 + kh*32,
                    sB + buf*16384 + (rg*2 + kh)*1024);
    };

    // ---- prologue: tile 0 -> buf 0
    stageB(0, 0, 0); stageB(0, 1, 0);
    stageA(0, 0, 0); stageA(0, 1, 0); stageA(0, 2, 0); stageA(0, 3, 0);
    asm volatile("s_waitcnt vmcnt(0)" ::: "memory");
    __builtin_amdgcn_s_barrier();

    const int NT = DMODEL / 64;   // 16
    for (int t = 0; t < NT; ++t) {
        const int  buf = t & 1;
        const int  k1  = (t + 1) * 64;
        const bool st  = (t + 1 < NT);
        char* const Ab = sA + buf*32768;
        char* const Bb = sB + buf*16384;

        // ================= phase 0: qm = 0 =================
        short8 bf[4][2], af[2][2];
#pragma unroll
        for (int j = 0; j < 4; ++j)
#pragma unroll
            for (int kh = 0; kh < 2; ++kh)
                bf[j][kh] = *(const short8*)(Bb + ((cw*4 + j)*2 + kh)*1024 + laneRd);
#pragma unroll
        for (int i = 0; i < 2; ++i)
#pragma unroll
            for (int kh = 0; kh < 2; ++kh)
                af[i][kh] = *(const short8*)(Ab + ((rw*2 + i)*2 + kh)*1024 + laneRd);

        if (st) { stageB(buf^1, 0, k1); stageB(buf^1, 1, k1);
                  stageA(buf^1, 0, k1); stageA(buf^1, 1, k1); }
        __builtin_amdgcn_s_barrier();

        __builtin_amdgcn_s_setprio(1);
#pragma unroll
        for (int i = 0; i < 2; ++i)
#pragma unroll
            for (int j = 0; j < 4; ++j) {
                acc[0][i][j] = __builtin_amdgcn_mfma_f32_16x16x32_bf16(
                    af[i][0], bf[j][0], acc[0][i][j], 0, 0, 0);
                acc[0][i][j] = __builtin_amdgcn_mfma_f32_16x16x32_bf16(
                    af[i][1], bf[j][1], acc[0][i][j], 0, 0, 0);
            }
        __builtin_amdgcn_s_setprio(0);

        if (st) { asm volatile("s_waitcnt vmcnt(4)" ::: "memory"); }
        else    { asm volatile("s_waitcnt vmcnt(0)" ::: "memory"); }
        __builtin_amdgcn_s_barrier();

        // ================= phase 1: qm = 1 =================
#pragma unroll
        for (int i = 0; i < 2; ++i)
#pragma unroll
            for (int kh = 0; kh < 2; ++kh)
                af[i][kh] = *(const short8*)(Ab + ((8 + rw*2 + i)*2 + kh)*1024 + laneRd);

        if (st) { stageA(buf^1, 2, k1); stageA(buf^1, 3, k1); }
        __builtin_amdgcn_s_barrier();

        __builtin_amdgcn_s_setprio(1);
#pragma unroll
        for (int i = 0; i < 2; ++i)
#pragma unroll
            for (int j = 0; j < 4; ++j) {
                acc[1][i][j] = __builtin_amdgcn_mfma_f32_16x16x32_bf16(
                    af[i][0], bf[j][0], acc[1][i][j], 0, 0, 0);
                acc[1][i][j] = __builtin_amdgcn_mfma_f32_16x16x32_bf16(
                    af[i][1], bf[j][1], acc[1][i][j], 0, 0, 0);
            }
        __builtin_amdgcn_s_setprio(0);

        if (st) { asm volatile("s_waitcnt vmcnt(2)" ::: "memory"); }
        else    { asm volatile("s_waitcnt vmcnt(0)" ::: "memory"); }
        __builtin_amdgcn_s_barrier();
    }

    // ---- epilogue
    float bv[4];
#pragma unroll
    for (int j = 0; j < 4; ++j)
        bv[j] = bias[bn*128 + cw*64 + j*16 + m16];

    if (QKV_MODE) {
        const int seg = bn >> 3;           // 0=Q(scaled), 1=K, 2=V(transposed)
        if (seg < 2) {
            bf16* Cout = (bf16*)(seg ? C1 : C0);
            const float sc = seg ? 1.0f : SCALE_Q;
#pragma unroll
            for (int q = 0; q < 2; ++q)
#pragma unroll
                for (int i = 0; i < 2; ++i)
#pragma unroll
                    for (int r = 0; r < 4; ++r) {
                        const int gm = bm*256 + q*128 + rw*32 + i*16 + quad*4 + r;
#pragma unroll
                        for (int j = 0; j < 4; ++j) {
                            const int cc = ((bn & 7)*128 + cw*64 + j*16 + m16);
                            Cout[(size_t)gm*DMODEL + cc] =
                                __float2bfloat16((acc[q][i][j][r] + bv[j]) * sc);
                        }
                    }
        } else {
            bf16* VT = (bf16*)C2;
#pragma unroll
            for (int q = 0; q < 2; ++q)
#pragma unroll
                for (int i = 0; i < 2; ++i) {
                    const int gm0 = bm*256 + q*128 + rw*32 + i*16 + quad*4;
                    const int bb = gm0 >> 11, t0 = gm0 & 2047;
#pragma unroll
                    for (int j = 0; j < 4; ++j) {
                        const int cv = (bn & 7)*128 + cw*64 + j*16 + m16;
                        const int hh = cv >> 6, dd = cv & 63;
                        union { unsigned long long u8; unsigned short us[4]; } o;
#pragma unroll
                        for (int r = 0; r < 4; ++r)
                            o.us[r] = f2bf_rne(acc[q][i][j][r] + bv[j]);
                        *(unsigned long long*)(VT
                            + ((size_t)((bb*NHEADS + hh)*DHEAD + dd))*SEQ + t0) = o.u8;
                    }
                }
        }
    } else {
        float* Cout = (float*)C0;
#pragma unroll
        for (int q = 0; q < 2; ++q)
#pragma unroll
            for (int i = 0; i < 2; ++i)
#pragma unroll
                for (int r = 0; r < 4; ++r) {
                    const int gm = bm*256 + q*128 + rw*32 + i*16 + quad*4 + r;
#pragma unroll
                    for (int j = 0; j < 4; ++j) {
                        const int cc = bn*128 + cw*64 + j*16 + m16;
                        Cout[(size_t)gm*DMODEL + cc] = acc[q][i][j][r] + bv[j];
                    }
                }
    }
}

// Distinct names so rocprof reports them separately
__global__ __launch_bounds__(512, 2) void qkv_proj(
    const float* __restrict__ bias, bf16* Q, bf16* K, bf16* VT)
{
    gemm_body<1>(nullptr, bias, Q, K, VT);
}
__global__ __launch_bounds__(512, 2) void out_proj(
    const void* __restrict__ Av, const float* __restrict__ bias, float* C)
{
    gemm_body<0>(Av, bias, C, nullptr, nullptr);
}

// ---------------------------------------------------------------------------
// MFMA flash attention v6 — v5 k-loop, re-gridded for occupancy.
// Round-6 lesson: 512 blocks = 2 blocks/CU (grid-limited); LDS shrink alone
// bought nothing. Now: block = ONE 128-row q-tile (4 waves), grid = 1024
// blocks -> 3 blocks/CU co-resident (LDS 46KB, floor(160/46)=3).
// Load balance via dispatch order: qt = 15 - (L>>6), longest blocks first.
// XCD locality: L&7 = bh&7 (64 = 0 mod 8) -> all 16 q-tiles of one (b,h)
// on one XCD, K/V stay L2-resident (FETCH was 27MB, keep).
// ---------------------------------------------------------------------------
__global__ __launch_bounds__(256, 3) void attn_mfma6(
    const bf16* __restrict__ Qg, const bf16* __restrict__ Kg,
    const bf16* __restrict__ VTg, bf16* __restrict__ Og)
{
    __shared__ alignas(16) unsigned short Kt[2][64][72];   // [buf][key][d]
    __shared__ alignas(16) unsigned short Vt[64][72];      // [d][key] single buf
    __shared__ alignas(16) unsigned short Ps[4][32][72];   // [wave][q][key]

    const int L  = blockIdx.x;
    const int qt = 15 - (L >> 6);      // longest q-tiles dispatched first
    const int bh = L & 63;
    const int b  = bh >> 4, h = bh & 15;

    const int tid = threadIdx.x;
    const int w = tid >> 6, lane = tid & 63;
    const int m16 = lane & 15, quad = lane >> 4;
    const int sr = tid >> 2, sc0 = (tid & 3) * 8;
    const size_t bhs = (size_t)(b*NHEADS + h);

    const int nkt = 2*qt + 2;
    const int qrow0 = qt*128 + w*32;

    short8 qf[2][2];
#pragma unroll
    for (int i = 0; i < 2; ++i)
#pragma unroll
        for (int c = 0; c < 2; ++c)
            qf[i][c] = *(const short8*)(Qg + (size_t)(b*SEQ + qrow0 + i*16 + m16)*DMODEL
                                        + h*DHEAD + c*32 + quad*8);

    floatx4 of[2][4];
    float mrow[2], lrow[2];
#pragma unroll
    for (int i = 0; i < 2; ++i) {
        mrow[i] = NEG_BIG; lrow[i] = 0.f;
#pragma unroll
        for (int nt = 0; nt < 4; ++nt) { of[i][nt][0]=0.f; of[i][nt][1]=0.f; of[i][nt][2]=0.f; of[i][nt][3]=0.f; }
    }

    // ---- stage tile 0
    {
        const bf16* kp = Kg  + (size_t)(b*SEQ + sr)*DMODEL + h*DHEAD + sc0;
        const bf16* vp = VTg + (bhs*DHEAD + sr)*SEQ + sc0;
        const uint4 a0 = *(const uint4*)kp, a1 = *(const uint4*)(kp + 32);
        const uint4 b0 = *(const uint4*)vp, b1 = *(const uint4*)(vp + 32);
        *(uint4*)&Kt[0][sr][sc0]      = a0;
        *(uint4*)&Kt[0][sr][sc0 + 32] = a1;
        *(uint4*)&Vt[sr][sc0]         = b0;
        *(uint4*)&Vt[sr][sc0 + 32]    = b1;
        __syncthreads();
    }

    for (int kt = 0; kt < nkt; ++kt) {
        const int buf = kt & 1;
        const int k064 = kt * 64;
        const bool pre = (kt + 1 < nkt);
        uint4 kr0, kr1, vr0, vr1;
        if (pre) {
            const bf16* kp = Kg  + (size_t)(b*SEQ + k064 + 64 + sr)*DMODEL + h*DHEAD + sc0;
            const bf16* vp = VTg + (bhs*DHEAD + sr)*SEQ + k064 + 64 + sc0;
            kr0 = *(const uint4*)kp; kr1 = *(const uint4*)(kp + 32);
            vr0 = *(const uint4*)vp; vr1 = *(const uint4*)(vp + 32);
        }

        // ---- S^T = K Q^T (16 MFMA): rows=key(quad*4+r, t4), cols=q(m16)
        floatx4 sf[2][4];
#pragma unroll
        for (int t4 = 0; t4 < 4; ++t4) {
            const short8 kf0 = *(const short8*)&Kt[buf][t4*16 + m16][quad*8];
            const short8 kf1 = *(const short8*)&Kt[buf][t4*16 + m16][32 + quad*8];
#pragma unroll
            for (int i = 0; i < 2; ++i) {
                floatx4 a; a[0]=0.f; a[1]=0.f; a[2]=0.f; a[3]=0.f;
                a = __builtin_amdgcn_mfma_f32_16x16x32_bf16(kf0, qf[i][0], a, 0, 0, 0);
                a = __builtin_amdgcn_mfma_f32_16x16x32_bf16(kf1, qf[i][1], a, 0, 0, 0);
                sf[i][t4] = a;
            }
        }

        // ---- online softmax (per lane = per q-column), defer-max
        const bool need_mask = (k064 + 63 > qrow0);
#pragma unroll
        for (int i = 0; i < 2; ++i) {
            if (need_mask) {
                const int qg = qrow0 + i*16 + m16;
#pragma unroll
                for (int t4 = 0; t4 < 4; ++t4)
#pragma unroll
                    for (int r = 0; r < 4; ++r)
                        if (k064 + t4*16 + quad*4 + r > qg) sf[i][t4][r] = NEG_BIG;
            }
            float mx = sf[i][0][0];
#pragma unroll
            for (int t4 = 0; t4 < 4; ++t4)
#pragma unroll
                for (int r = 0; r < 4; ++r) mx = fmaxf(mx, sf[i][t4][r]);
            mx = fmaxf(mx, __shfl_xor(mx, 16));
            mx = fmaxf(mx, __shfl_xor(mx, 32));

            // defer-max: only rescale when the tile max meaningfully grows.
            // S is in base-2 log units; THR=8 bounds P by 2^8=256 (safe).
            if (__any(mx > mrow[i] + 8.f)) {
                const float mnew  = fmaxf(mrow[i], mx);
                const float alpha = exp2f(mrow[i] - mnew);
                mrow[i] = mnew;
                lrow[i] *= alpha;
#pragma unroll
                for (int nt = 0; nt < 4; ++nt)
#pragma unroll
                    for (int r = 0; r < 4; ++r) of[i][nt][r] *= alpha;
            }

            float rs = 0.f;
#pragma unroll
            for (int t4 = 0; t4 < 4; ++t4) {
#pragma unroll
                for (int r = 0; r < 4; ++r) {
                    const float pv = exp2f(sf[i][t4][r] - mrow[i]);
                    sf[i][t4][r] = pv;
                    rs += pv;
                }
            }
            rs += __shfl_xor(rs, 16);
            rs += __shfl_xor(rs, 32);
            lrow[i] += rs;

            // P^T -> LDS: 4 consecutive keys per b64 store
#pragma unroll
            for (int t4 = 0; t4 < 4; ++t4) {
                union { unsigned long long u8; unsigned short us[4]; } o;
#pragma unroll
                for (int r = 0; r < 4; ++r) o.us[r] = f2bf_rne(sf[i][t4][r]);
                *(unsigned long long*)&Ps[w][i*16 + m16][t4*16 + quad*4] = o.u8;
            }
        }

        // ---- O^T += V^T P^T (16 MFMA); Ps wave-local, Vt single-buf
        short8 pf[2][2];
#pragma unroll
        for (int i = 0; i < 2; ++i)
#pragma unroll
            for (int c = 0; c < 2; ++c)
                pf[i][c] = *(const short8*)&Ps[w][i*16 + m16][c*32 + quad*8];
#pragma unroll
        for (int nt = 0; nt < 4; ++nt) {
            const short8 vf0 = *(const short8*)&Vt[nt*16 + m16][quad*8];
            const short8 vf1 = *(const short8*)&Vt[nt*16 + m16][32 + quad*8];
#pragma unroll
            for (int i = 0; i < 2; ++i) {
                of[i][nt] = __builtin_amdgcn_mfma_f32_16x16x32_bf16(vf0, pf[i][0], of[i][nt], 0, 0, 0);
                of[i][nt] = __builtin_amdgcn_mfma_f32_16x16x32_bf16(vf1, pf[i][1], of[i][nt], 0, 0, 0);
            }
        }

        // all waves done reading Vt before it is overwritten
        __syncthreads();
        if (pre) {
            *(uint4*)&Kt[buf^1][sr][sc0]      = kr0;
            *(uint4*)&Kt[buf^1][sr][sc0 + 32] = kr1;
            *(uint4*)&Vt[sr][sc0]             = vr0;
            *(uint4*)&Vt[sr][sc0 + 32]        = vr1;
        }
        __syncthreads();
    }

    // ---- normalize + store O: lane owns row q, dims nt*16+quad*4+{0..3}
#pragma unroll
    for (int i = 0; i < 2; ++i) {
        const float rl = 1.f / fmaxf(lrow[i], 1e-20f);
        const size_t rowbase = (size_t)(b*SEQ + qrow0 + i*16 + m16)*DMODEL + h*DHEAD;
#pragma unroll
        for (int nt = 0; nt < 4; ++nt) {
            union { unsigned long long u8; unsigned short us[4]; } o;
#pragma unroll
            for (int r = 0; r < 4; ++r) o.us[r] = f2bf_rne(of[i][nt][r] * rl);
            *(unsigned long long*)(Og + rowbase + nt*16 + quad*4) = o.u8;
        }
    }
}

__global__ void diag_fill(float* out, int n, float val) {
    int i = blockIdx.x*blockDim.x + threadIdx.x;
    if (i < n) out[i] = val;
}

// ---------------------------------------------------------------------------
extern "C" void kernel_launch(void* const* d_in, const int* in_sizes, int n_in,
                              void* d_out, int out_size, void* d_ws, size_t ws_size,
                              hipStream_t stream) {
    const float* x     = (const float*)d_in[0];
    const float* W_qkv = (const float*)d_in[1];
    const float* b_qkv = (const float*)d_in[2];
    const float* W_out = (const float*)d_in[3];
    const float* b_out = (const float*)d_in[4];

    if (ws_size < WS_NEED) {
        const float val = 100.f + (float)(ws_size >> 20);
        diag_fill<<<(out_size + 255)/256, 256, 0, stream>>>((float*)d_out, out_size, val);
        return;
    }

    bf16* Qb  = (bf16*)d_out;                                // d_out lo: Q (pre-scaled)
    bf16* VTb = (bf16*)d_out + (size_t)MROWS*DMODEL;         // d_out hi: VT
    bf16* Kb  = (bf16*)d_ws;                                 // ws lo: K
    bf16* Ob  = (bf16*)d_ws + (size_t)MROWS*DMODEL;          // ws hi: O

    // 0) casts (both weight transposes fused into one launch)
    cast_x<<<MROWS*DMODEL/2048, 256, 0, stream>>>(x);
    {
        dim3 g(64, DMODEL/64);
        transcast_w2<<<g, 256, 0, stream>>>(W_qkv, W_out);
    }
    // 1) fused QKV projection; Q pre-scaled; V pre-transposed
    qkv_proj<<<768, 512, 0, stream>>>(b_qkv, Qb, Kb, VTb);
    // 2) flash attention v6 (1024 blocks, 3 blocks/CU, longest-first)
    attn_mfma6<<<1024, 256, 0, stream>>>(Qb, Kb, VTb, Ob);
    // 3) output projection: O bf16 -> fp32 d_out
    out_proj<<<256, 512, 0, stream>>>(Ob, b_out, (float*)d_out);
}

// Round 9
// 264.818 us; speedup vs baseline: 1.1401x; 1.0174x over previous
//
#include <hip/hip_runtime.h>
#include <hip/hip_bf16.h>

#define BATCH   4
#define SEQ     2048
#define DMODEL  1024
#define NHEADS  16
#define DHEAD   64
#define MROWS   (BATCH*SEQ)        // 8192
#define QKV_N   (3*DMODEL)         // 3072
#define NEG_BIG (-1.0e30f)
#define WS_NEED ((size_t)MROWS * 2*DMODEL * sizeof(__hip_bfloat16))  // 33,554,432
#define SCALE_Q 0.18033688011112042f   // 0.125 * log2(e); folded into Q at projection

using bf16 = __hip_bfloat16;
typedef __attribute__((ext_vector_type(8))) short short8;
typedef __attribute__((ext_vector_type(4))) float floatx4;

// Static device buffers (module BSS; no hipMalloc)
__device__ __align__(16) unsigned short g_wqT[QKV_N * DMODEL];   // W_qkv^T bf16
__device__ __align__(16) unsigned short g_woT[DMODEL * DMODEL];  // W_out^T bf16
__device__ __align__(16) unsigned short g_xb [MROWS * DMODEL];   // x bf16

__device__ __forceinline__ unsigned short f2bf_rne(float f) {
    union { bf16 b; unsigned short u; } t;
    t.b = __float2bfloat16(f);
    return t.u;
}

// async global->LDS, 16B per lane; LDS dest = wave-uniform base + lane*16
__device__ __forceinline__ void gload_lds16(const void* g, void* l) {
    __builtin_amdgcn_global_load_lds(
        (const __attribute__((address_space(1))) unsigned*)g,
        (__attribute__((address_space(3))) unsigned*)l, 16, 0, 0);
}

// ---------------------------------------------------------------------------
// x fp32 -> bf16
// ---------------------------------------------------------------------------
__global__ __launch_bounds__(256) void cast_x(const float* __restrict__ x) {
    const size_t i = ((size_t)blockIdx.x*256 + threadIdx.x)*8;
    const float4 a = *(const float4*)(x + i);
    const float4 b = *(const float4*)(x + i + 4);
    union { uint4 u4; unsigned short us[8]; } o;
    o.us[0]=f2bf_rne(a.x); o.us[1]=f2bf_rne(a.y); o.us[2]=f2bf_rne(a.z); o.us[3]=f2bf_rne(a.w);
    o.us[4]=f2bf_rne(b.x); o.us[5]=f2bf_rne(b.y); o.us[6]=f2bf_rne(b.z); o.us[7]=f2bf_rne(b.w);
    *(uint4*)(g_xb + i) = o.u4;
}

// ---------------------------------------------------------------------------
// Weight transpose + cast (both weights in ONE launch):
// blocks [0,48): W_qkv fp32 [1024][3072] -> g_wqT [3072][1024]
// blocks [48,64): W_out fp32 [1024][1024] -> g_woT [1024][1024]
// ---------------------------------------------------------------------------
__global__ __launch_bounds__(256) void transcast_w2(
    const float* __restrict__ Wq, const float* __restrict__ Wo)
{
    const int bx = blockIdx.x;
    const float* W;
    unsigned short* dst;
    int N, n0;
    if (bx < 48) { W = Wq; dst = g_wqT; N = QKV_N;  n0 = bx * 64; }
    else         { W = Wo; dst = g_woT; N = DMODEL; n0 = (bx - 48) * 64; }
    const int k0 = blockIdx.y * 64;

    __shared__ unsigned short T[64][72];
    const int tid = threadIdx.x;
    const int r = tid >> 2, c0 = (tid & 3) * 16;

#pragma unroll
    for (int it = 0; it < 4; ++it) {
        const float4 v = *(const float4*)(W + (size_t)(k0 + r)*N + n0 + c0 + it*4);
        T[r][c0 + it*4 + 0] = f2bf_rne(v.x);
        T[r][c0 + it*4 + 1] = f2bf_rne(v.y);
        T[r][c0 + it*4 + 2] = f2bf_rne(v.z);
        T[r][c0 + it*4 + 3] = f2bf_rne(v.w);
    }
    __syncthreads();
    const int nr = tid >> 2, kc0 = (tid & 3) * 16;
#pragma unroll
    for (int it = 0; it < 2; ++it) {
        union { uint4 u4; unsigned short us[8]; } o;
#pragma unroll
        for (int j = 0; j < 8; j++) o.us[j] = T[kc0 + it*8 + j][nr];
        *(uint4*)(dst + (size_t)(n0 + nr)*DMODEL + k0 + kc0 + it*8) = o.u4;
    }
}

// ---------------------------------------------------------------------------
// qkv_proj: 256x256 BK=64, 4-phase/K-tile deep-pipelined MFMA GEMM (m201
// schedule). 8 waves (512 thr), wave grid 2M x 4N, per-wave 128x64 output.
// LDS 128 KiB: A 2buf x 32KB, B 2buf x 32KB (1KB subtiles, idx rg*2+kh;
// within subtile 16B chunk c of row r at slot c^((r>>1)&3) -> conflict-free
// ds_read_b128). Round-8 lesson: the 2-phase schedule stalls ~500cy/phase
// because vmcnt targets loads issued only 1 phase (~350cy) earlier vs HBM
// ~900cy. Here every wait targets loads >=3 phases (~900cy+) old.
// Phase q of tile t (2 gload_lds/wave/phase staging tile t+1):
//  p0 (mh0,kh0): read bf[4]kh0+af[4]; stage B'kh0; bar; 16 MFMA; vmcnt; bar
//  p1 (mh1,kh0): read af[4];          stage A'mh0; bar; 16 MFMA; vmcnt; bar
//  p2 (mh0,kh1): read bf[4]kh1+af[4]; stage A'mh1; bar; 16 MFMA; vmcnt; bar
//  p3 (mh1,kh1): read af[4];          stage B'kh1; bar; 16 MFMA; vmcnt; bar
// Ledger (issue stream B0,A0,A1,B1 per tile, 2 loads each):
//  p0-end vmcnt(4): drains A1(t-1) [3 phases old]  (needed by p1)
//  p1-end vmcnt(4): drains B1(t-1) [3 phases old]  (needed by p2)
//  p2-end vmcnt(6): no-op cap                      (p3's A1 long drained)
//  p3-end vmcnt(4): drains B0,A0(t) [4,3 phases]   (needed by p0(t+1))
// Tail t=15 (no issues): p0-end vmcnt(2), p1-end vmcnt(0), p2-end vmcnt(0).
// Epilogue splits Q|K|VT: seg = bn>>2 (0=Q scaled, 1=K, 2=V transposed).
// ---------------------------------------------------------------------------
__global__ __launch_bounds__(512, 2) void qkv_proj(
    const float* __restrict__ bias, bf16* __restrict__ Qo,
    bf16* __restrict__ Ko, bf16* __restrict__ VT)
{
    const unsigned short* A  = g_xb;
    const unsigned short* BT = g_wqT;
    constexpr int NBN = 12;            // 3072/256
    constexpr int NWG = 32 * NBN;      // 384

    __shared__ __align__(16) char smem[131072];   // A: 2x32KB @0; B: 2x32KB @64K
    char* const sA = smem;
    char* const sB = smem + 65536;

    // XCD-aware swizzle (NWG%8==0): consecutive blocks share bm, sweep bn
    const int orig = blockIdx.x;
    const int wgid = (orig & 7) * (NWG >> 3) + (orig >> 3);
    const int bm = wgid / NBN, bn = wgid % NBN;

    const int tid  = threadIdx.x;
    const int w    = tid >> 6, lane = tid & 63;
    const int m16  = lane & 15, quad = lane >> 4;
    const int rw   = w >> 2, cw = w & 3;          // 2M x 4N

    // staging lane decomposition: slot chunk (r,c) holds data chunk c^((r>>1)&3)
    const int rL = lane >> 2;
    const int cD = (lane & 3) ^ ((lane >> 3) & 3);
    const unsigned short* gA = A  + (size_t)(bm*256 + rL)*DMODEL + cD*8;
    const unsigned short* gB = BT + (size_t)(bn*256 + rL)*DMODEL + cD*8;

    // frag-read lane offset (swizzled)
    const int laneRd = m16*64 + (quad ^ ((m16 >> 1) & 3))*16;

    floatx4 acc[8][4];   // [mf][nf]
#pragma unroll
    for (int i = 0; i < 8; ++i)
#pragma unroll
        for (int j = 0; j < 4; ++j) {
            acc[i][j][0]=0.f; acc[i][j][1]=0.f; acc[i][j][2]=0.f; acc[i][j][3]=0.f;
        }

    auto stA = [&](int buf, int rg, int kh, int k0) {
        gload_lds16(gA + (size_t)(rg*16)*DMODEL + k0 + kh*32,
                    sA + buf*32768 + (rg*2 + kh)*1024);
    };
    auto stB = [&](int buf, int rg, int kh, int k0) {
        gload_lds16(gB + (size_t)(rg*16)*DMODEL + k0 + kh*32,
                    sB + buf*32768 + (rg*2 + kh)*1024);
    };

    // ---- prologue: tile 0 -> buf 0 (full 64KB, 8 gloads/wave)
    stB(0, 2*w, 0, 0);   stB(0, 2*w+1, 0, 0);
    stA(0, w,   0, 0);   stA(0, w,   1, 0);
    stA(0, 8+w, 0, 0);   stA(0, 8+w, 1, 0);
    stB(0, 2*w, 1, 0);   stB(0, 2*w+1, 1, 0);
    asm volatile("s_waitcnt vmcnt(0)" ::: "memory");
    __builtin_amdgcn_s_barrier();

    const int NT = DMODEL / 64;   // 16
    for (int t = 0; t < NT; ++t) {
        const int  buf = t & 1;
        const int  k1  = (t + 1) * 64;
        const bool st  = (t + 1 < NT);
        char* const Ab = sA + buf*32768;
        char* const Bb = sB + buf*32768;

        short8 bf[4], af[4];

        // ============ p0: (mh0, kh0) ============
#pragma unroll
        for (int j = 0; j < 4; ++j)
            bf[j] = *(const short8*)(Bb + ((cw*4 + j)*2 + 0)*1024 + laneRd);
#pragma unroll
        for (int i = 0; i < 4; ++i)
            af[i] = *(const short8*)(Ab + ((rw*8 + i)*2 + 0)*1024 + laneRd);
        if (st) { stB(buf^1, 2*w, 0, k1); stB(buf^1, 2*w+1, 0, k1); }
        __builtin_amdgcn_s_barrier();
        __builtin_amdgcn_s_setprio(1);
#pragma unroll
        for (int i = 0; i < 4; ++i)
#pragma unroll
            for (int j = 0; j < 4; ++j)
                acc[i][j] = __builtin_amdgcn_mfma_f32_16x16x32_bf16(af[i], bf[j], acc[i][j], 0, 0, 0);
        __builtin_amdgcn_s_setprio(0);
        if (st) { asm volatile("s_waitcnt vmcnt(4)" ::: "memory"); }
        else    { asm volatile("s_waitcnt vmcnt(2)" ::: "memory"); }
        __builtin_amdgcn_s_barrier();

        // ============ p1: (mh1, kh0) ============
#pragma unroll
        for (int i = 0; i < 4; ++i)
            af[i] = *(const short8*)(Ab + ((rw*8 + 4 + i)*2 + 0)*1024 + laneRd);
        if (st) { stA(buf^1, w, 0, k1); stA(buf^1, w, 1, k1); }
        __builtin_amdgcn_s_barrier();
        __builtin_amdgcn_s_setprio(1);
#pragma unroll
        for (int i = 0; i < 4; ++i)
#pragma unroll
            for (int j = 0; j < 4; ++j)
                acc[4+i][j] = __builtin_amdgcn_mfma_f32_16x16x32_bf16(af[i], bf[j], acc[4+i][j], 0, 0, 0);
        __builtin_amdgcn_s_setprio(0);
        if (st) { asm volatile("s_waitcnt vmcnt(4)" ::: "memory"); }
        else    { asm volatile("s_waitcnt vmcnt(0)" ::: "memory"); }
        __builtin_amdgcn_s_barrier();

        // ============ p2: (mh0, kh1) ============
#pragma unroll
        for (int j = 0; j < 4; ++j)
            bf[j] = *(const short8*)(Bb + ((cw*4 + j)*2 + 1)*1024 + laneRd);
#pragma unroll
        for (int i = 0; i < 4; ++i)
            af[i] = *(const short8*)(Ab + ((rw*8 + i)*2 + 1)*1024 + laneRd);
        if (st) { stA(buf^1, 8+w, 0, k1); stA(buf^1, 8+w, 1, k1); }
        __builtin_amdgcn_s_barrier();
        __builtin_amdgcn_s_setprio(1);
#pragma unroll
        for (int i = 0; i < 4; ++i)
#pragma unroll
            for (int j = 0; j < 4; ++j)
                acc[i][j] = __builtin_amdgcn_mfma_f32_16x16x32_bf16(af[i], bf[j], acc[i][j], 0, 0, 0);
        __builtin_amdgcn_s_setprio(0);
        if (st) { asm volatile("s_waitcnt vmcnt(6)" ::: "memory"); }
        else    { asm volatile("s_waitcnt vmcnt(0)" ::: "memory"); }
        __builtin_amdgcn_s_barrier();

        // ============ p3: (mh1, kh1) ============
#pragma unroll
        for (int i = 0; i < 4; ++i)
            af[i] = *(const short8*)(Ab + ((rw*8 + 4 + i)*2 + 1)*1024 + laneRd);
        if (st) { stB(buf^1, 2*w, 1, k1); stB(buf^1, 2*w+1, 1, k1); }
        __builtin_amdgcn_s_barrier();
        __builtin_amdgcn_s_setprio(1);
#pragma unroll
        for (int i = 0; i < 4; ++i)
#pragma unroll
            for (int j = 0; j < 4; ++j)
                acc[4+i][j] = __builtin_amdgcn_mfma_f32_16x16x32_bf16(af[i], bf[j], acc[4+i][j], 0, 0, 0);
        __builtin_amdgcn_s_setprio(0);
        if (st) {
            asm volatile("s_waitcnt vmcnt(4)" ::: "memory");
            __builtin_amdgcn_s_barrier();
        }
    }

    // ---- epilogue: seg = 0(Q,scaled) / 1(K) / 2(V transposed)
    float bv[4];
#pragma unroll
    for (int j = 0; j < 4; ++j)
        bv[j] = bias[bn*256 + cw*64 + j*16 + m16];

    const int seg = bn >> 2;
    if (seg < 2) {
        bf16* Cout = seg ? Ko : Qo;
        const float sc = seg ? 1.0f : SCALE_Q;
#pragma unroll
        for (int mf = 0; mf < 8; ++mf)
#pragma unroll
            for (int r = 0; r < 4; ++r) {
                const int gm = bm*256 + rw*128 + mf*16 + quad*4 + r;
#pragma unroll
                for (int j = 0; j < 4; ++j) {
                    const int cc = (bn*256 + cw*64 + j*16 + m16) & 1023;
                    Cout[(size_t)gm*DMODEL + cc] =
                        __float2bfloat16((acc[mf][j][r] + bv[j]) * sc);
                }
            }
    } else {
#pragma unroll
        for (int mf = 0; mf < 8; ++mf) {
            const int gm0 = bm*256 + rw*128 + mf*16 + quad*4;
            const int bb = gm0 >> 11, t0 = gm0 & 2047;
#pragma unroll
            for (int j = 0; j < 4; ++j) {
                const int cv = ((bn & 3)*256 + cw*64 + j*16 + m16);
                const int hh = cv >> 6, dd = cv & 63;
                union { unsigned long long u8; unsigned short us[4]; } o;
#pragma unroll
                for (int r = 0; r < 4; ++r)
                    o.us[r] = f2bf_rne(acc[mf][j][r] + bv[j]);
                *(unsigned long long*)(VT
                    + ((size_t)((bb*NHEADS + hh)*DHEAD + dd))*SEQ + t0) = o.u8;
            }
        }
    }
}

// ---------------------------------------------------------------------------
// out_proj: UNCHANGED 256x128 BK=64 2-phase kernel (working, ~1 round @256).
// ---------------------------------------------------------------------------
__global__ __launch_bounds__(512, 2) void out_proj(
    const void* __restrict__ Av, const float* __restrict__ bias, float* C)
{
    const unsigned short* A  = (const unsigned short*)Av;
    const unsigned short* BT = g_woT;
    constexpr int NBN = 8;
    constexpr int NWG = NBN * 32;

    __shared__ __align__(16) char smem[98304];  // A: 2x32KB @0; B: 2x16KB @65536
    char* const sA = smem;
    char* const sB = smem + 65536;

    const int orig = blockIdx.x;
    const int wgid = (orig & 7) * (NWG >> 3) + (orig >> 3);
    const int bm = wgid / NBN, bn = wgid % NBN;

    const int tid  = threadIdx.x;
    const int w    = tid >> 6, lane = tid & 63;
    const int m16  = lane & 15, quad = lane >> 4;
    const int rw   = w >> 1, cw = w & 1;

    const int rL = lane >> 2;
    const int cD = (lane & 3) ^ ((lane >> 3) & 3);
    const unsigned short* gA = A  + (size_t)(bm*256 + rL)*DMODEL + cD*8;
    const unsigned short* gB = BT + (size_t)(bn*128 + rL)*DMODEL + cD*8;

    const int laneRd = m16*64 + (quad ^ ((m16 >> 1) & 3))*16;

    floatx4 acc[2][2][4];
#pragma unroll
    for (int q = 0; q < 2; ++q)
#pragma unroll
        for (int i = 0; i < 2; ++i)
#pragma unroll
            for (int j = 0; j < 4; ++j) {
                acc[q][i][j][0]=0.f; acc[q][i][j][1]=0.f;
                acc[q][i][j][2]=0.f; acc[q][i][j][3]=0.f;
            }

    auto stageA = [&](int buf, int a, int k0) {
        const int rg = 4*a + (w >> 1), kh = w & 1;
        gload_lds16(gA + (size_t)(rg*16)*DMODEL + k0 + kh*32,
                    sA + buf*32768 + (rg*2 + kh)*1024);
    };
    auto stageB = [&](int buf, int b, int k0) {
        const int rg = 4*b + (w >> 1), kh = w & 1;
        gload_lds16(gB + (size_t)(rg*16)*DMODEL + k0 + kh*32,
                    sB + buf*16384 + (rg*2 + kh)*1024);
    };

    stageB(0, 0, 0); stageB(0, 1, 0);
    stageA(0, 0, 0); stageA(0, 1, 0); stageA(0, 2, 0); stageA(0, 3, 0);
    asm volatile("s_waitcnt vmcnt(0)" ::: "memory");
    __builtin_amdgcn_s_barrier();

    const int NT = DMODEL / 64;
    for (int t = 0; t < NT; ++t) {
        const int  buf = t & 1;
        const int  k1  = (t + 1) * 64;
        const bool st  = (t + 1 < NT);
        char* const Ab = sA + buf*32768;
        char* const Bb = sB + buf*16384;

        short8 bf[4][2], af[2][2];
#pragma unroll
        for (int j = 0; j < 4; ++j)
#pragma unroll
            for (int kh = 0; kh < 2; ++kh)
                bf[j][kh] = *(const short8*)(Bb + ((cw*4 + j)*2 + kh)*1024 + laneRd);
#pragma unroll
        for (int i = 0; i < 2; ++i)
#pragma unroll
            for (int kh = 0; kh < 2; ++kh)
                af[i][kh] = *(const short8*)(Ab + ((rw*2 + i)*2 + kh)*1024 + laneRd);

        if (st) { stageB(buf^1, 0, k1); stageB(buf^1, 1, k1);
                  stageA(buf^1, 0, k1); stageA(buf^1, 1, k1); }
        __builtin_amdgcn_s_barrier();

        __builtin_amdgcn_s_setprio(1);
#pragma unroll
        for (int i = 0; i < 2; ++i)
#pragma unroll
            for (int j = 0; j < 4; ++j) {
                acc[0][i][j] = __builtin_amdgcn_mfma_f32_16x16x32_bf16(
                    af[i][0], bf[j][0], acc[0][i][j], 0, 0, 0);
                acc[0][i][j] = __builtin_amdgcn_mfma_f32_16x16x32_bf16(
                    af[i][1], bf[j][1], acc[0][i][j], 0, 0, 0);
            }
        __builtin_amdgcn_s_setprio(0);

        if (st) { asm volatile("s_waitcnt vmcnt(4)" ::: "memory"); }
        else    { asm volatile("s_waitcnt vmcnt(0)" ::: "memory"); }
        __builtin_amdgcn_s_barrier();

#pragma unroll
        for (int i = 0; i < 2; ++i)
#pragma unroll
            for (int kh = 0; kh < 2; ++kh)
                af[i][kh] = *(const short8*)(Ab + ((8 + rw*2 + i)*2 + kh)*1024 + laneRd);

        if (st) { stageA(buf^1, 2, k1); stageA(buf^1, 3, k1); }
        __builtin_amdgcn_s_barrier();

        __builtin_amdgcn_s_setprio(1);
#pragma unroll
        for (int i = 0; i < 2; ++i)
#pragma unroll
            for (int j = 0; j < 4; ++j) {
                acc[1][i][j] = __builtin_amdgcn_mfma_f32_16x16x32_bf16(
                    af[i][0], bf[j][0], acc[1][i][j], 0, 0, 0);
                acc[1][i][j] = __builtin_amdgcn_mfma_f32_16x16x32_bf16(
                    af[i][1], bf[j][1], acc[1][i][j], 0, 0, 0);
            }
        __builtin_amdgcn_s_setprio(0);

        if (st) { asm volatile("s_waitcnt vmcnt(2)" ::: "memory"); }
        else    { asm volatile("s_waitcnt vmcnt(0)" ::: "memory"); }
        __builtin_amdgcn_s_barrier();
    }

    float bv[4];
#pragma unroll
    for (int j = 0; j < 4; ++j)
        bv[j] = bias[bn*128 + cw*64 + j*16 + m16];

#pragma unroll
    for (int q = 0; q < 2; ++q)
#pragma unroll
        for (int i = 0; i < 2; ++i)
#pragma unroll
            for (int r = 0; r < 4; ++r) {
                const int gm = bm*256 + q*128 + rw*32 + i*16 + quad*4 + r;
#pragma unroll
                for (int j = 0; j < 4; ++j) {
                    const int cc = bn*128 + cw*64 + j*16 + m16;
                    C[(size_t)gm*DMODEL + cc] = acc[q][i][j][r] + bv[j];
                }
            }
}

// ---------------------------------------------------------------------------
// MFMA flash attention v6 — UNCHANGED (83.5 us, verified round 8).
// ---------------------------------------------------------------------------
__global__ __launch_bounds__(256, 3) void attn_mfma6(
    const bf16* __restrict__ Qg, const bf16* __restrict__ Kg,
    const bf16* __restrict__ VTg, bf16* __restrict__ Og)
{
    __shared__ alignas(16) unsigned short Kt[2][64][72];   // [buf][key][d]
    __shared__ alignas(16) unsigned short Vt[64][72];      // [d][key] single buf
    __shared__ alignas(16) unsigned short Ps[4][32][72];   // [wave][q][key]

    const int L  = blockIdx.x;
    const int qt = 15 - (L >> 6);      // longest q-tiles dispatched first
    const int bh = L & 63;
    const int b  = bh >> 4, h = bh & 15;

    const int tid = threadIdx.x;
    const int w = tid >> 6, lane = tid & 63;
    const int m16 = lane & 15, quad = lane >> 4;
    const int sr = tid >> 2, sc0 = (tid & 3) * 8;
    const size_t bhs = (size_t)(b*NHEADS + h);

    const int nkt = 2*qt + 2;
    const int qrow0 = qt*128 + w*32;

    short8 qf[2][2];
#pragma unroll
    for (int i = 0; i < 2; ++i)
#pragma unroll
        for (int c = 0; c < 2; ++c)
            qf[i][c] = *(const short8*)(Qg + (size_t)(b*SEQ + qrow0 + i*16 + m16)*DMODEL
                                        + h*DHEAD + c*32 + quad*8);

    floatx4 of[2][4];
    float mrow[2], lrow[2];
#pragma unroll
    for (int i = 0; i < 2; ++i) {
        mrow[i] = NEG_BIG; lrow[i] = 0.f;
#pragma unroll
        for (int nt = 0; nt < 4; ++nt) { of[i][nt][0]=0.f; of[i][nt][1]=0.f; of[i][nt][2]=0.f; of[i][nt][3]=0.f; }
    }

    // ---- stage tile 0
    {
        const bf16* kp = Kg  + (size_t)(b*SEQ + sr)*DMODEL + h*DHEAD + sc0;
        const bf16* vp = VTg + (bhs*DHEAD + sr)*SEQ + sc0;
        const uint4 a0 = *(const uint4*)kp, a1 = *(const uint4*)(kp + 32);
        const uint4 b0 = *(const uint4*)vp, b1 = *(const uint4*)(vp + 32);
        *(uint4*)&Kt[0][sr][sc0]      = a0;
        *(uint4*)&Kt[0][sr][sc0 + 32] = a1;
        *(uint4*)&Vt[sr][sc0]         = b0;
        *(uint4*)&Vt[sr][sc0 + 32]    = b1;
        __syncthreads();
    }

    for (int kt = 0; kt < nkt; ++kt) {
        const int buf = kt & 1;
        const int k064 = kt * 64;
        const bool pre = (kt + 1 < nkt);
        uint4 kr0, kr1, vr0, vr1;
        if (pre) {
            const bf16* kp = Kg  + (size_t)(b*SEQ + k064 + 64 + sr)*DMODEL + h*DHEAD + sc0;
            const bf16* vp = VTg + (bhs*DHEAD + sr)*SEQ + k064 + 64 + sc0;
            kr0 = *(const uint4*)kp; kr1 = *(const uint4*)(kp + 32);
            vr0 = *(const uint4*)vp; vr1 = *(const uint4*)(vp + 32);
        }

        // ---- S^T = K Q^T (16 MFMA): rows=key(quad*4+r, t4), cols=q(m16)
        floatx4 sf[2][4];
#pragma unroll
        for (int t4 = 0; t4 < 4; ++t4) {
            const short8 kf0 = *(const short8*)&Kt[buf][t4*16 + m16][quad*8];
            const short8 kf1 = *(const short8*)&Kt[buf][t4*16 + m16][32 + quad*8];
#pragma unroll
            for (int i = 0; i < 2; ++i) {
                floatx4 a; a[0]=0.f; a[1]=0.f; a[2]=0.f; a[3]=0.f;
                a = __builtin_amdgcn_mfma_f32_16x16x32_bf16(kf0, qf[i][0], a, 0, 0, 0);
                a = __builtin_amdgcn_mfma_f32_16x16x32_bf16(kf1, qf[i][1], a, 0, 0, 0);
                sf[i][t4] = a;
            }
        }

        // ---- online softmax (per lane = per q-column), defer-max
        const bool need_mask = (k064 + 63 > qrow0);
#pragma unroll
        for (int i = 0; i < 2; ++i) {
            if (need_mask) {
                const int qg = qrow0 + i*16 + m16;
#pragma unroll
                for (int t4 = 0; t4 < 4; ++t4)
#pragma unroll
                    for (int r = 0; r < 4; ++r)
                        if (k064 + t4*16 + quad*4 + r > qg) sf[i][t4][r] = NEG_BIG;
            }
            float mx = sf[i][0][0];
#pragma unroll
            for (int t4 = 0; t4 < 4; ++t4)
#pragma unroll
                for (int r = 0; r < 4; ++r) mx = fmaxf(mx, sf[i][t4][r]);
            mx = fmaxf(mx, __shfl_xor(mx, 16));
            mx = fmaxf(mx, __shfl_xor(mx, 32));

            if (__any(mx > mrow[i] + 8.f)) {
                const float mnew  = fmaxf(mrow[i], mx);
                const float alpha = exp2f(mrow[i] - mnew);
                mrow[i] = mnew;
                lrow[i] *= alpha;
#pragma unroll
                for (int nt = 0; nt < 4; ++nt)
#pragma unroll
                    for (int r = 0; r < 4; ++r) of[i][nt][r] *= alpha;
            }

            float rs = 0.f;
#pragma unroll
            for (int t4 = 0; t4 < 4; ++t4) {
#pragma unroll
                for (int r = 0; r < 4; ++r) {
                    const float pv = exp2f(sf[i][t4][r] - mrow[i]);
                    sf[i][t4][r] = pv;
                    rs += pv;
                }
            }
            rs += __shfl_xor(rs, 16);
            rs += __shfl_xor(rs, 32);
            lrow[i] += rs;

#pragma unroll
            for (int t4 = 0; t4 < 4; ++t4) {
                union { unsigned long long u8; unsigned short us[4]; } o;
#pragma unroll
                for (int r = 0; r < 4; ++r) o.us[r] = f2bf_rne(sf[i][t4][r]);
                *(unsigned long long*)&Ps[w][i*16 + m16][t4*16 + quad*4] = o.u8;
            }
        }

        // ---- O^T += V^T P^T (16 MFMA); Ps wave-local, Vt single-buf
        short8 pf[2][2];
#pragma unroll
        for (int i = 0; i < 2; ++i)
#pragma unroll
            for (int c = 0; c < 2; ++c)
                pf[i][c] = *(const short8*)&Ps[w][i*16 + m16][c*32 + quad*8];
#pragma unroll
        for (int nt = 0; nt < 4; ++nt) {
            const short8 vf0 = *(const short8*)&Vt[nt*16 + m16][quad*8];
            const short8 vf1 = *(const short8*)&Vt[nt*16 + m16][32 + quad*8];
#pragma unroll
            for (int i = 0; i < 2; ++i) {
                of[i][nt] = __builtin_amdgcn_mfma_f32_16x16x32_bf16(vf0, pf[i][0], of[i][nt], 0, 0, 0);
                of[i][nt] = __builtin_amdgcn_mfma_f32_16x16x32_bf16(vf1, pf[i][1], of[i][nt], 0, 0, 0);
            }
        }

        __syncthreads();
        if (pre) {
            *(uint4*)&Kt[buf^1][sr][sc0]      = kr0;
            *(uint4*)&Kt[buf^1][sr][sc0 + 32] = kr1;
            *(uint4*)&Vt[sr][sc0]             = vr0;
            *(uint4*)&Vt[sr][sc0 + 32]        = vr1;
        }
        __syncthreads();
    }

    // ---- normalize + store O
#pragma unroll
    for (int i = 0; i < 2; ++i) {
        const float rl = 1.f / fmaxf(lrow[i], 1e-20f);
        const size_t rowbase = (size_t)(b*SEQ + qrow0 + i*16 + m16)*DMODEL + h*DHEAD;
#pragma unroll
        for (int nt = 0; nt < 4; ++nt) {
            union { unsigned long long u8; unsigned short us[4]; } o;
#pragma unroll
            for (int r = 0; r < 4; ++r) o.us[r] = f2bf_rne(of[i][nt][r] * rl);
            *(unsigned long long*)(Og + rowbase + nt*16 + quad*4) = o.u8;
        }
    }
}

__global__ void diag_fill(float* out, int n, float val) {
    int i = blockIdx.x*blockDim.x + threadIdx.x;
    if (i < n) out[i] = val;
}

// ---------------------------------------------------------------------------
extern "C" void kernel_launch(void* const* d_in, const int* in_sizes, int n_in,
                              void* d_out, int out_size, void* d_ws, size_t ws_size,
                              hipStream_t stream) {
    const float* x     = (const float*)d_in[0];
    const float* W_qkv = (const float*)d_in[1];
    const float* b_qkv = (const float*)d_in[2];
    const float* W_out = (const float*)d_in[3];
    const float* b_out = (const float*)d_in[4];

    if (ws_size < WS_NEED) {
        const float val = 100.f + (float)(ws_size >> 20);
        diag_fill<<<(out_size + 255)/256, 256, 0, stream>>>((float*)d_out, out_size, val);
        return;
    }

    bf16* Qb  = (bf16*)d_out;                                // d_out lo: Q (pre-scaled)
    bf16* VTb = (bf16*)d_out + (size_t)MROWS*DMODEL;         // d_out hi: VT
    bf16* Kb  = (bf16*)d_ws;                                 // ws lo: K
    bf16* Ob  = (bf16*)d_ws + (size_t)MROWS*DMODEL;          // ws hi: O

    // 0) casts (both weight transposes fused into one launch)
    cast_x<<<MROWS*DMODEL/2048, 256, 0, stream>>>(x);
    {
        dim3 g(64, DMODEL/64);
        transcast_w2<<<g, 256, 0, stream>>>(W_qkv, W_out);
    }
    // 1) fused QKV projection (256^2 4-phase deep-pipelined, 384 blocks)
    qkv_proj<<<384, 512, 0, stream>>>(b_qkv, Qb, Kb, VTb);
    // 2) flash attention v6 (unchanged)
    attn_mfma6<<<1024, 256, 0, stream>>>(Qb, Kb, VTb, Ob);
    // 3) output projection (unchanged)
    out_proj<<<256, 512, 0, stream>>>(Ob, b_out, (float*)d_out);
}